// Round 4
// baseline (170.277 us; speedup 1.0000x reference)
//
#include <hip/hip_runtime.h>

// SAModule (PointNet++ SA), fused f32-input kernel. R9:
//  - R8 post-mortem: VALU-issue dropped 49->40us but stalls grew; kernel is now
//    barrier/latency-bound (~35 barriers/block, ~300-500cy work between them;
//    3 blocks/CU pinned by LDS).
//  - R9: 32-col weight steps (2x8KB dbuf, LDS 49152, still 3 blocks/CU) => 16 steps,
//    half the barriers, 12-16 MFMA per step; weight step 0 committed before phase A;
//    s_setprio(1) around MFMA nests (3 co-resident blocks are phase-heterogeneous).

typedef unsigned short u16;
typedef unsigned int u32;
typedef unsigned long long u64;
typedef __bf16 bf16x8 __attribute__((ext_vector_type(8)));
typedef float floatx4 __attribute__((ext_vector_type(4)));

#define PCLOUD 4096
#define DIN    64
#define MCENT  8192
#define KNBR   32
#define CAP    448

// smem map (49152 B): sA = [0,32768) 128 rows x 256B; sW dbuf = [32768,49152) 2 x 8KB.
// phase A/B overlay inside the sA region (dead before gather writes sA):
#define OFF_LIST  0        // u64[4][CAP] = 14336
#define OFF_HIST  14336    // u32[4][32]  = 512
#define OFF_NBRL  14848    // int[4][32]  = 512
#define OFF_CNT   15360    // int[4] acnt | int[4] cnt2
#define OFF_CEN   15392    // float4[4] centers (x,y,z,|c|^2)
#define OFF_BCL   15456    // int[4] cloud ids

__device__ inline u16 f2bf(float f) {          // RNE, no scrub (inputs finite)
    u32 b = __float_as_uint(f);
    b += 0x7fffu + ((b >> 16) & 1u);
    return (u16)(b >> 16);
}
__device__ inline u32 cvtpk(float a, float b) {  // packed {bf16(a), bf16(b)<<16}, RNE
    u32 r;
    asm("v_cvt_pk_bf16_f32 %0, %1, %2" : "=v"(r) : "v"(a), "v"(b));
    return r;
}
__device__ inline u64 wave_min_u64(u64 v) {
    #pragma unroll
    for (int off = 32; off; off >>= 1) {
        u64 o = __shfl_xor((unsigned long long)v, off);
        if (o < v) v = o;
    }
    return v;
}
__device__ inline u64 d2key(float d2, int j) {
    u32 u = __float_as_uint(d2);
    u = (u & 0x80000000u) ? ~u : (u | 0x80000000u);   // order-preserving map
    return ((u64)u << 32) | (u32)j;
}
__device__ inline int key_bucket(u64 k) {
    u32 hi = (u32)(k >> 32);
    if (hi < 0x80000000u) return 0;                    // d2 <= -0
    float d2 = __uint_as_float(hi & 0x7fffffffu);
    int b = (int)(d2 * 800.0f);                        // 32 buckets over [0, 0.04]
    return b > 31 ? 31 : b;
}

// ---- prep: weights -> bf16 B-fragment images in ws (exact LDS bit layout) ----
// image block b of 16 cols (256 uint4): chunk[n*16 + (kc^(n&7))] = {bf16 W[kc*8+j][n0+n]}
// ws = 32 contiguous 4KB blocks: b=0..7 W1, 8..15 W2, 16..31 W3. A 32-col GEMM step g
// uses blocks {2g, 2g+1} = one contiguous 8KB slab, verbatim LDS image.
__global__ void prep_kernel(const float* __restrict__ W1, const float* __restrict__ W2,
                            const float* __restrict__ W3, uint4* __restrict__ ws) {
    int t = blockIdx.x * 256 + threadIdx.x;   // 0..8191
    int g = t >> 11, r = t & 2047;
    int n = r >> 4, kc = r & 15;
    const float* W; int rs, n0, krows;
    if (g == 0)      { W = W1; rs = 128; n0 = 0;   krows = 67;  }
    else if (g == 1) { W = W2; rs = 128; n0 = 0;   krows = 128; }
    else if (g == 2) { W = W3; rs = 256; n0 = 0;   krows = 128; }
    else             { W = W3; rs = 256; n0 = 128; krows = 128; }
    u16 e[8];
    #pragma unroll
    for (int j = 0; j < 8; j++) {
        int k = kc * 8 + j;
        e[j] = (k < krows) ? f2bf(W[(size_t)k * rs + n0 + n]) : (u16)0;
    }
    ws[(g << 11) + (n << 4) + (kc ^ (n & 7))] = *(const uint4*)e;
}

// Commit one 8KB (32-col) weight step into a buffer. WS: two linear b128 writes of the
// preloaded regs. !WS fallback: compute the bf16 packing on the fly.
template <bool WS>
__device__ __forceinline__ void commitW32(int g, uint4 ld0, uint4 ld1,
                                          uint4* __restrict__ buf, int tid,
                                          const float* __restrict__ W1,
                                          const float* __restrict__ W2,
                                          const float* __restrict__ W3) {
    if constexpr (WS) {
        buf[tid] = ld0;
        buf[256 + tid] = ld1;
    } else {
        #pragma unroll
        for (int h = 0; h < 2; h++) {
            int b = g * 2 + h;
            const float* W; int rs, n0, krows;
            if (b < 8)       { W = W1; rs = 128; n0 = b * 16;        krows = 67;  }
            else if (b < 16) { W = W2; rs = 128; n0 = (b - 8) * 16;  krows = 128; }
            else             { W = W3; rs = 256; n0 = (b - 16) * 16; krows = 128; }
            int n = tid >> 4, kc = tid & 15;
            u16 e[8];
            #pragma unroll
            for (int j = 0; j < 8; j++) {
                int k = kc * 8 + j;
                e[j] = (k < krows) ? f2bf(W[(size_t)k * rs + n0 + n]) : (u16)0;
            }
            buf[h * 256 + (n << 4) + (kc ^ (n & 7))] = *(const uint4*)e;
        }
    }
}

__device__ __forceinline__ void push_hit(int c, float d2, int j,
                                         int* acnt, u64* lists) {
    int p = atomicAdd(&acnt[c], 1);
    if (p < CAP) lists[c * CAP + p] = d2key(d2, j);
}

template <bool WS>
__global__ __launch_bounds__(256, 3) void sa_kernel(
    const float* __restrict__ x, const float* __restrict__ pos,
    const int* __restrict__ batch, const int* __restrict__ idx,
    const float* __restrict__ W1, const float* __restrict__ b1,
    const float* __restrict__ W2, const float* __restrict__ b2,
    const float* __restrict__ W3, const float* __restrict__ b3,
    const uint4* __restrict__ ws4, float* __restrict__ out) {
    __shared__ __align__(16) char smem[49152];
    u64*  lists = (u64*)(smem + OFF_LIST);
    u32*  hist  = (u32*)(smem + OFF_HIST);
    int*  nbrl  = (int*)(smem + OFF_NBRL);
    int*  acnt  = (int*)(smem + OFF_CNT);
    int*  cnt2  = (int*)(smem + OFF_CNT + 16);
    float4* cen = (float4*)(smem + OFF_CEN);
    int*  bcls  = (int*)(smem + OFF_BCL);

    uint4* sA4  = (uint4*)smem;
    uint4* sWb0 = (uint4*)(smem + 32768);
    uint4* sWb1 = (uint4*)(smem + 40960);

    int tid = threadIdx.x, w = tid >> 6, l = tid & 63;
    uint4 ld0 = {}, ld1 = {};
    if constexpr (WS) { ld0 = ws4[tid]; ld1 = ws4[256 + tid]; }   // step 0 (issued early)

    int bid = blockIdx.x;
    int m0 = ((bid & 7) << 10) + ((bid >> 3) << 2);   // XCD-friendly: bid%8 ~ cloud
    int m = m0 + w;
    int ic = idx[m] & (8 * PCLOUD - 1);
    float cx = pos[ic * 3], cy = pos[ic * 3 + 1], cz = pos[ic * 3 + 2];
    float sc = __fadd_rn(__fadd_rn(__fmul_rn(cx, cx), __fmul_rn(cy, cy)), __fmul_rn(cz, cz));
    int bcl = batch[ic] & 7;
    int base = bcl << 12;
    const float R2 = 0.04f;

    if (l == 0) { cen[w] = make_float4(cx, cy, cz, sc); bcls[w] = bcl; }
    if (tid < 4) { acnt[tid] = 0; cnt2[tid] = 0; }
    if (l == 1) {
        float* o1 = out + MCENT * 256;
        o1[m * 3] = cx; o1[m * 3 + 1] = cy; o1[m * 3 + 2] = cz;
        (o1 + MCENT * 3)[m] = (float)bcl;
    }
    // stage weight step 0 now (sW region is disjoint from the phase A/B overlay)
    commitW32<WS>(0, ld0, ld1, sWb0, tid, W1, W2, W3);
    __syncthreads();

    // ---- phase A: cooperative scan, float4 loads, each point tested vs 4 centers ----
    bool uni = (bcls[0] == bcls[1]) && (bcls[1] == bcls[2]) && (bcls[2] == bcls[3]);
    if (uni) {
        float4 cA = cen[0], cB = cen[1], cC = cen[2], cD = cen[3];
        int jb = bcls[0] << 12;
        const float4* pb4 = (const float4*)(pos + (size_t)jb * 3);

#define TEST1(CEN, CI, SP, PX, PY, PZ, J) { \
    float dt = __fadd_rn(__fadd_rn(__fmul_rn(CEN.x, PX), __fmul_rn(CEN.y, PY)), __fmul_rn(CEN.z, PZ)); \
    float d2 = __fsub_rn(__fadd_rn(CEN.w, SP), __fmul_rn(2.0f, dt)); \
    if (d2 <= R2) push_hit(CI, d2, J, acnt, lists); }
#define TESTP(PX, PY, PZ, J) { \
    float sp = __fadd_rn(__fadd_rn(__fmul_rn(PX, PX), __fmul_rn(PY, PY)), __fmul_rn(PZ, PZ)); \
    TEST1(cA, 0, sp, PX, PY, PZ, J) \
    TEST1(cB, 1, sp, PX, PY, PZ, J) \
    TEST1(cC, 2, sp, PX, PY, PZ, J) \
    TEST1(cD, 3, sp, PX, PY, PZ, J) }

        #pragma unroll
        for (int it = 0; it < 4; it++) {
            int tq = it * 256 + tid;                   // quad-point index 0..1023
            float4 q0 = pb4[tq * 3], q1 = pb4[tq * 3 + 1], q2 = pb4[tq * 3 + 2];
            int j0 = jb + tq * 4;
            TESTP(q0.x, q0.y, q0.z, j0)
            TESTP(q0.w, q1.x, q1.y, j0 + 1)
            TESTP(q1.z, q1.w, q2.x, j0 + 2)
            TESTP(q2.y, q2.z, q2.w, j0 + 3)
        }
#undef TESTP
#undef TEST1
    } else {
        // rare mixed-cloud block: per-wave scan of own cloud from global
        for (int t = l; t < PCLOUD; t += 64) {
            int j = base + t;
            float px = pos[j * 3], py = pos[j * 3 + 1], pz = pos[j * 3 + 2];
            float sp = __fadd_rn(__fadd_rn(__fmul_rn(px, px), __fmul_rn(py, py)), __fmul_rn(pz, pz));
            float dt = __fadd_rn(__fadd_rn(__fmul_rn(cx, px), __fmul_rn(cy, py)), __fmul_rn(cz, pz));
            float d2 = __fsub_rn(__fadd_rn(sc, sp), __fmul_rn(2.0f, dt));
            if (d2 <= R2) push_hit(w, d2, j, acnt, lists);
        }
    }
    __syncthreads();   // cross-wave list visibility

    int c = acnt[w];
    int nsel = c < KNBR ? c : KNBR;
    u64* mylist = lists + w * CAP;

    // ---- phase B: select the 32 smallest (d2,idx) keys (set only; order free) ----
    int selj = -1;
    if (c <= KNBR) {
        if (l < c) selj = (int)(u32)mylist[l];
    } else if (c <= CAP) {
        u64 kk[7];
        int bk[7];
        if (l < 32) hist[w * 32 + l] = 0;              // same-wave LDS: ordered
        #pragma unroll
        for (int i = 0; i < 7; i++) kk[i] = (l + i * 64 < c) ? mylist[l + i * 64] : ~0ull;
        #pragma unroll
        for (int i = 0; i < 7; i++) {                  // build d2 histogram (this wave only)
            bk[i] = 32;
            if (kk[i] != ~0ull) {
                bk[i] = key_bucket(kk[i]);
                atomicAdd(&hist[w * 32 + bk[i]], 1u);
            }
        }
        int hv = (l < 32) ? (int)hist[w * 32 + l] : 0; // atomics above are same-wave: ordered
        #pragma unroll
        for (int off = 1; off <= 16; off <<= 1) {   // inclusive scan, lanes 0..31
            int o = __shfl_up(hv, off);
            if (l >= off) hv += o;
        }
        u64 ge = __ballot((l < 32) && (hv >= KNBR));
        int B = __ffsll((unsigned long long)ge) - 1;        // threshold bucket
        int S = (B == 0) ? 0 : __shfl(hv, B - 1);           // count strictly below B
        #pragma unroll
        for (int i = 0; i < 7; i++) {                       // bulk-select below B
            if (kk[i] != ~0ull) {
                if (bk[i] < B) { int p = atomicAdd(&cnt2[w], 1); nbrl[w * 32 + p] = (int)(u32)kk[i]; }
                if (bk[i] != B) kk[i] = ~0ull;              // keep only bucket-B keys
            }
        }
        int need = KNBR - S;                                // expected ~4-12 rounds
        u64 last = 0;
        for (int r = 0; r < need; r++) {
            u64 mn = ~0ull;
            #pragma unroll
            for (int i = 0; i < 7; i++) if (kk[i] > last && kk[i] < mn) mn = kk[i];
            mn = wave_min_u64(mn);
            if (l == 0) nbrl[w * 32 + S + r] = (int)(u32)mn;
            last = mn;
        }
        if (l < KNBR) selj = nbrl[w * 32 + l];
    } else {
        // overflow fallback (never taken for uniform data): streaming 32-round argmin
        u64 last = 0;
        for (int r = 0; r < KNBR; r++) {
            u64 mn = ~0ull;
            for (int t = l; t < PCLOUD; t += 64) {
                int j = base + t;
                float px = pos[j * 3], py = pos[j * 3 + 1], pz = pos[j * 3 + 2];
                float sp = __fadd_rn(__fadd_rn(__fmul_rn(px, px), __fmul_rn(py, py)), __fmul_rn(pz, pz));
                float dt = __fadd_rn(__fadd_rn(__fmul_rn(cx, px), __fmul_rn(cy, py)), __fmul_rn(cz, pz));
                float d2 = __fsub_rn(__fadd_rn(sc, sp), __fmul_rn(2.0f, dt));
                if (d2 <= R2) { u64 kf = d2key(d2, j); if (kf > last && kf < mn) mn = kf; }
            }
            mn = wave_min_u64(mn);
            if (l == r) selj = (int)(u32)mn;
            last = mn;
        }
    }
    __syncthreads();   // lists/hist dead; sA region becomes the GEMM A-tile

    if constexpr (WS) { ld0 = ws4[512 + tid]; ld1 = ws4[768 + tid]; }   // step 1

    // ---- gather 32 feat rows per wave (XOR 16B-chunk swizzle); rows are wave-private ----
    {
        int h = l & 1, rl = l >> 1;
        int row = w * 32 + rl;
        int j = __shfl(selj, rl);
        int xv = row & 7;
        uint4* dst = sA4 + row * 16;
        uint4 z; z.x = z.y = z.z = z.w = 0;
        if (j >= 0) {
            const float4* sx = (const float4*)(x + (size_t)j * DIN);
            int c0lo = h ? 6 : 0, c0hi = h ? 8 : 6;
            for (int c0 = c0lo; c0 < c0hi; c0++) {
                float4 f0 = sx[c0 * 2], f1 = sx[c0 * 2 + 1];
                uint4 pv;
                pv.x = cvtpk(f0.x, f0.y); pv.y = cvtpk(f0.z, f0.w);
                pv.z = cvtpk(f1.x, f1.y); pv.w = cvtpk(f1.z, f1.w);
                dst[c0 ^ xv] = pv;
            }
            if (h == 1) {
                float rx = pos[j * 3] - cx, ry = pos[j * 3 + 1] - cy, rz = pos[j * 3 + 2] - cz;
                uint4 rc; rc.x = cvtpk(rx, ry); rc.y = cvtpk(rz, 0.0f); rc.z = 0; rc.w = 0;
                dst[8 ^ xv] = rc;
                dst[9 ^ xv] = z; dst[10 ^ xv] = z; dst[11 ^ xv] = z;
            }
        } else {
            int c0lo = h ? 6 : 0, c0hi = h ? 12 : 6;
            for (int c0 = c0lo; c0 < c0hi; c0++) dst[c0 ^ xv] = z;
        }
    }
    __syncthreads();

    int m16 = l & 15, quad = l >> 4;
    int r0 = w * 32;
    const floatx4 vzero = {0.f, 0.f, 0.f, 0.f};

    // ==== GEMM1: h1 = relu(feat @ W1 + b1), K=96, swapped operands, 4 x 32-col steps ====
    {
        bf16x8 a1[3][2];
        #pragma unroll
        for (int ki = 0; ki < 3; ki++)
            #pragma unroll
            for (int t = 0; t < 2; t++) {
                int row = r0 + t * 16 + m16;
                a1[ki][t] = __builtin_bit_cast(bf16x8, sA4[row * 16 + ((ki * 4 + quad) ^ (row & 7))]);
            }
        #pragma unroll 2
        for (int s = 0; s < 4; s++) {
            uint4* buf  = (s & 1) ? sWb1 : sWb0;
            uint4* nbuf = (s & 1) ? sWb0 : sWb1;
            floatx4 acc[2][2] = {{vzero, vzero}, {vzero, vzero}};
            __builtin_amdgcn_s_setprio(1);
            #pragma unroll
            for (int ki = 0; ki < 3; ki++) {
                int cb = ki * 4 + quad;
                #pragma unroll
                for (int cc = 0; cc < 2; cc++) {
                    bf16x8 b = __builtin_bit_cast(bf16x8, buf[cc * 256 + (m16 << 4) + (cb ^ (m16 & 7))]);
                    #pragma unroll
                    for (int t = 0; t < 2; t++)
                        acc[t][cc] = __builtin_amdgcn_mfma_f32_16x16x32_bf16(b, a1[ki][t], acc[t][cc], 0, 0, 0);
                }
            }
            __builtin_amdgcn_s_setprio(0);
            #pragma unroll
            for (int t = 0; t < 2; t++) {
                int rr = r0 + t * 16 + m16;
                #pragma unroll
                for (int cc = 0; cc < 2; cc++) {
                    float4 bb = ((const float4*)b1)[s * 8 + cc * 4 + quad];
                    uint2 pv;
                    pv.x = cvtpk(fmaxf(acc[t][cc][0] + bb.x, 0.f), fmaxf(acc[t][cc][1] + bb.y, 0.f));
                    pv.y = cvtpk(fmaxf(acc[t][cc][2] + bb.z, 0.f), fmaxf(acc[t][cc][3] + bb.w, 0.f));
                    *(uint2*)(smem + rr * 256 + (((s * 4 + cc * 2 + (quad >> 1)) ^ (rr & 7)) << 4)
                              + ((quad & 1) << 3)) = pv;
                }
            }
            commitW32<WS>(s + 1, ld0, ld1, nbuf, tid, W1, W2, W3);
            if constexpr (WS) { ld0 = ws4[(s + 2) * 512 + tid]; ld1 = ws4[(s + 2) * 512 + 256 + tid]; }
            __syncthreads();
        }
    }

    // ==== GEMM2: h2 = relu(h1 @ W2 + b2), K=128, swapped operands, 4 x 32-col steps ====
    {
        bf16x8 a2[4][2];
        #pragma unroll
        for (int ki = 0; ki < 4; ki++)
            #pragma unroll
            for (int t = 0; t < 2; t++) {
                int row = r0 + t * 16 + m16;
                a2[ki][t] = __builtin_bit_cast(bf16x8, sA4[row * 16 + ((ki * 4 + quad) ^ (row & 7))]);
            }
        #pragma unroll 2
        for (int s = 0; s < 4; s++) {
            uint4* buf  = (s & 1) ? sWb1 : sWb0;
            uint4* nbuf = (s & 1) ? sWb0 : sWb1;
            floatx4 acc[2][2] = {{vzero, vzero}, {vzero, vzero}};
            __builtin_amdgcn_s_setprio(1);
            #pragma unroll
            for (int ki = 0; ki < 4; ki++) {
                int cb = ki * 4 + quad;
                #pragma unroll
                for (int cc = 0; cc < 2; cc++) {
                    bf16x8 b = __builtin_bit_cast(bf16x8, buf[cc * 256 + (m16 << 4) + (cb ^ (m16 & 7))]);
                    #pragma unroll
                    for (int t = 0; t < 2; t++)
                        acc[t][cc] = __builtin_amdgcn_mfma_f32_16x16x32_bf16(b, a2[ki][t], acc[t][cc], 0, 0, 0);
                }
            }
            __builtin_amdgcn_s_setprio(0);
            #pragma unroll
            for (int t = 0; t < 2; t++) {
                int rr = r0 + t * 16 + m16;
                #pragma unroll
                for (int cc = 0; cc < 2; cc++) {
                    float4 bb = ((const float4*)b2)[s * 8 + cc * 4 + quad];
                    uint2 pv;
                    pv.x = cvtpk(fmaxf(acc[t][cc][0] + bb.x, 0.f), fmaxf(acc[t][cc][1] + bb.y, 0.f));
                    pv.y = cvtpk(fmaxf(acc[t][cc][2] + bb.z, 0.f), fmaxf(acc[t][cc][3] + bb.w, 0.f));
                    *(uint2*)(smem + rr * 256 + (((s * 4 + cc * 2 + (quad >> 1)) ^ (rr & 7)) << 4)
                              + ((quad & 1) << 3)) = pv;
                }
            }
            commitW32<WS>(s + 5, ld0, ld1, nbuf, tid, W1, W2, W3);
            if constexpr (WS) { ld0 = ws4[(s + 6) * 512 + tid]; ld1 = ws4[(s + 6) * 512 + 256 + tid]; }
            __syncthreads();
        }
    }

    // == GEMM3: out = maxpool(relu(h2 @ W3 + b3)), K=128, N=256, 8 x 32-col steps ==
    {
        bf16x8 a3[4][2];
        #pragma unroll
        for (int ki = 0; ki < 4; ki++)
            #pragma unroll
            for (int t = 0; t < 2; t++) {
                int row = r0 + t * 16 + m16;
                a3[ki][t] = __builtin_bit_cast(bf16x8, sA4[row * 16 + ((ki * 4 + quad) ^ (row & 7))]);
            }
        #pragma unroll 2
        for (int s = 0; s < 8; s++) {
            uint4* buf  = (s & 1) ? sWb1 : sWb0;
            uint4* nbuf = (s & 1) ? sWb0 : sWb1;
            floatx4 acc[2][2] = {{vzero, vzero}, {vzero, vzero}};
            __builtin_amdgcn_s_setprio(1);
            #pragma unroll
            for (int ki = 0; ki < 4; ki++) {
                int cb = ki * 4 + quad;
                #pragma unroll
                for (int cc = 0; cc < 2; cc++) {
                    bf16x8 b = __builtin_bit_cast(bf16x8, buf[cc * 256 + (m16 << 4) + (cb ^ (m16 & 7))]);
                    #pragma unroll
                    for (int t = 0; t < 2; t++)
                        acc[t][cc] = __builtin_amdgcn_mfma_f32_16x16x32_bf16(a3[ki][t], b, acc[t][cc], 0, 0, 0);
                }
            }
            __builtin_amdgcn_s_setprio(0);
            #pragma unroll
            for (int cc = 0; cc < 2; cc++) {
                int col = s * 32 + cc * 16 + m16;
                float bias = b3[col];
                float mv = 0.0f;   // post-ReLU max over >=1 valid nbr is >= 0
                #pragma unroll
                for (int t = 0; t < 2; t++)
                    #pragma unroll
                    for (int i = 0; i < 4; i++) {
                        int k = t * 16 + quad * 4 + i;
                        float v = fmaxf(acc[t][cc][i] + bias, 0.0f);
                        if (k < nsel) mv = fmaxf(mv, v);
                    }
                mv = fmaxf(mv, __shfl_xor(mv, 16));
                mv = fmaxf(mv, __shfl_xor(mv, 32));
                if (quad == 0) out[(m0 + w) * 256 + col] = mv;
            }
            if (s < 7) {
                commitW32<WS>(s + 9, ld0, ld1, nbuf, tid, W1, W2, W3);
                if constexpr (WS) {
                    if (s < 6) { ld0 = ws4[(s + 10) * 512 + tid]; ld1 = ws4[(s + 10) * 512 + 256 + tid]; }
                }
                __syncthreads();
            }
        }
    }
}

extern "C" void kernel_launch(void* const* d_in, const int* in_sizes, int n_in,
                              void* d_out, int out_size, void* d_ws, size_t ws_size,
                              hipStream_t stream) {
    const float* x     = (const float*)d_in[0];
    const float* pos   = (const float*)d_in[1];
    const int*   batch = (const int*)d_in[2];
    const int*   idx   = (const int*)d_in[3];
    const float* W1    = (const float*)d_in[4];
    const float* b1    = (const float*)d_in[5];
    const float* W2    = (const float*)d_in[6];
    const float* b2    = (const float*)d_in[7];
    const float* W3    = (const float*)d_in[8];
    const float* b3    = (const float*)d_in[9];
    float* out = (float*)d_out;
    uint4* ws4 = (uint4*)d_ws;

    if (ws_size >= 131072) {
        hipLaunchKernelGGL(prep_kernel, dim3(32), dim3(256), 0, stream, W1, W2, W3, ws4);
        hipLaunchKernelGGL((sa_kernel<true>), dim3(MCENT / 4), dim3(256), 0, stream,
                           x, pos, batch, idx, W1, b1, W2, b2, W3, b3, ws4, out);
    } else {
        hipLaunchKernelGGL((sa_kernel<false>), dim3(MCENT / 4), dim3(256), 0, stream,
                           x, pos, batch, idx, W1, b1, W2, b2, W3, b3, ws4, out);
    }
}

// Round 5
// 163.657 us; speedup vs baseline: 1.0404x; 1.0404x over previous
//
#include <hip/hip_runtime.h>

// SAModule (PointNet++ SA), fused f32-input kernel. R10:
//  - R9 post-mortem: usable LDS/CU is ~128KB (not 160); 48KB LDS => 2 blocks/CU,
//    occupancy 37.5->26.6% ate the barrier win.
//  - R10: weights are read DIRECTLY from the prepped ws image in L2 (one uint4 per
//    lane per MFMA, exact fragment layout; 1-group register prefetch). No sW in LDS:
//    * LDS = 32KB exactly => 4 blocks/CU (50% occupancy cap)
//    * sA rows are wave-private => ZERO barriers after phase B (3 barriers total)
//    * ws = 128KB, L2-resident on all XCDs; +1GB L2 reads @ ~1.6TB/s/XCD << 4.3 ceiling

typedef unsigned short u16;
typedef unsigned int u32;
typedef unsigned long long u64;
typedef __bf16 bf16x8 __attribute__((ext_vector_type(8)));
typedef float floatx4 __attribute__((ext_vector_type(4)));

#define PCLOUD 4096
#define DIN    64
#define MCENT  8192
#define KNBR   32
#define CAP    448

// smem map (32768 B): sA = 128 rows x 256B. phase A/B overlay (dead before gather):
#define OFF_LIST  0        // u64[4][CAP] = 14336
#define OFF_HIST  14336    // u32[4][32]  = 512
#define OFF_NBRL  14848    // int[4][32]  = 512
#define OFF_CNT   15360    // int[4] acnt | int[4] cnt2
#define OFF_CEN   15392    // float4[4] centers (x,y,z,|c|^2)
#define OFF_BCL   15456    // int[4] cloud ids

__device__ inline u16 f2bf(float f) {          // RNE, no scrub (inputs finite)
    u32 b = __float_as_uint(f);
    b += 0x7fffu + ((b >> 16) & 1u);
    return (u16)(b >> 16);
}
__device__ inline u32 cvtpk(float a, float b) {  // packed {bf16(a), bf16(b)<<16}, RNE
    u32 r;
    asm("v_cvt_pk_bf16_f32 %0, %1, %2" : "=v"(r) : "v"(a), "v"(b));
    return r;
}
__device__ inline u64 wave_min_u64(u64 v) {
    #pragma unroll
    for (int off = 32; off; off >>= 1) {
        u64 o = __shfl_xor((unsigned long long)v, off);
        if (o < v) v = o;
    }
    return v;
}
__device__ inline u64 d2key(float d2, int j) {
    u32 u = __float_as_uint(d2);
    u = (u & 0x80000000u) ? ~u : (u | 0x80000000u);   // order-preserving map
    return ((u64)u << 32) | (u32)j;
}
__device__ inline int key_bucket(u64 k) {
    u32 hi = (u32)(k >> 32);
    if (hi < 0x80000000u) return 0;                    // d2 <= -0
    float d2 = __uint_as_float(hi & 0x7fffffffu);
    int b = (int)(d2 * 800.0f);                        // 32 buckets over [0, 0.04]
    return b > 31 ? 31 : b;
}

// ---- prep: weights -> bf16 B-fragment images in ws (consumed directly from L2) ----
// 32 contiguous 4KB blocks of 16 cols each: blk 0..7 = W1, 8..15 = W2, 16..31 = W3.
// blk layout (256 uint4): chunk[n*16 + (kc^(n&7))] = {bf16 W[kc*8+j][col0+n], j=0..7}
__global__ void prep_kernel(const float* __restrict__ W1, const float* __restrict__ W2,
                            const float* __restrict__ W3, uint4* __restrict__ ws) {
    int t = blockIdx.x * 256 + threadIdx.x;   // 0..8191
    int g = t >> 11, r = t & 2047;
    int n = r >> 4, kc = r & 15;
    const float* W; int rs, n0, krows;
    if (g == 0)      { W = W1; rs = 128; n0 = 0;   krows = 67;  }
    else if (g == 1) { W = W2; rs = 128; n0 = 0;   krows = 128; }
    else if (g == 2) { W = W3; rs = 256; n0 = 0;   krows = 128; }
    else             { W = W3; rs = 256; n0 = 128; krows = 128; }
    u16 e[8];
    #pragma unroll
    for (int j = 0; j < 8; j++) {
        int k = kc * 8 + j;
        e[j] = (k < krows) ? f2bf(W[(size_t)k * rs + n0 + n]) : (u16)0;
    }
    ws[(g << 11) + (n << 4) + (kc ^ (n & 7))] = *(const uint4*)e;
}

// One B-fragment (8 bf16 of col `col0+m16`, k-rows cb*8..cb*8+7), straight from ws/L2.
__device__ __forceinline__ uint4 ldB_ws(const uint4* __restrict__ ws4, int blk, int cb, int m16) {
    return ws4[blk * 256 + (m16 << 4) + (cb ^ (m16 & 7))];
}
// Workspace-less fallback: gather the column from W in f32 and pack (correctness path).
__device__ __forceinline__ uint4 ldB_fb(const float* __restrict__ W, int rs, int col,
                                        int cb, int krows) {
    u16 e[8];
    #pragma unroll
    for (int j = 0; j < 8; j++) {
        int k = cb * 8 + j;
        e[j] = (k < krows) ? f2bf(W[(size_t)k * rs + col]) : (u16)0;
    }
    return *(const uint4*)e;
}

__device__ __forceinline__ void push_hit(int c, float d2, int j,
                                         int* acnt, u64* lists) {
    int p = atomicAdd(&acnt[c], 1);
    if (p < CAP) lists[c * CAP + p] = d2key(d2, j);
}

template <bool WS>
__global__ __launch_bounds__(256, 4) void sa_kernel(
    const float* __restrict__ x, const float* __restrict__ pos,
    const int* __restrict__ batch, const int* __restrict__ idx,
    const float* __restrict__ W1, const float* __restrict__ b1,
    const float* __restrict__ W2, const float* __restrict__ b2,
    const float* __restrict__ W3, const float* __restrict__ b3,
    const uint4* __restrict__ ws4, float* __restrict__ out) {
    __shared__ __align__(16) char smem[32768];
    u64*  lists = (u64*)(smem + OFF_LIST);
    u32*  hist  = (u32*)(smem + OFF_HIST);
    int*  nbrl  = (int*)(smem + OFF_NBRL);
    int*  acnt  = (int*)(smem + OFF_CNT);
    int*  cnt2  = (int*)(smem + OFF_CNT + 16);
    float4* cen = (float4*)(smem + OFF_CEN);
    int*  bcls  = (int*)(smem + OFF_BCL);
    uint4* sA4  = (uint4*)smem;

    int tid = threadIdx.x, w = tid >> 6, l = tid & 63;
    int bid = blockIdx.x;
    int m0 = ((bid & 7) << 10) + ((bid >> 3) << 2);   // XCD-friendly: bid%8 ~ cloud
    int m = m0 + w;
    int ic = idx[m] & (8 * PCLOUD - 1);
    float cx = pos[ic * 3], cy = pos[ic * 3 + 1], cz = pos[ic * 3 + 2];
    float sc = __fadd_rn(__fadd_rn(__fmul_rn(cx, cx), __fmul_rn(cy, cy)), __fmul_rn(cz, cz));
    int bcl = batch[ic] & 7;
    int base = bcl << 12;
    const float R2 = 0.04f;

    if (l == 0) { cen[w] = make_float4(cx, cy, cz, sc); bcls[w] = bcl; }
    if (tid < 4) { acnt[tid] = 0; cnt2[tid] = 0; }
    if (l == 1) {
        float* o1 = out + MCENT * 256;
        o1[m * 3] = cx; o1[m * 3 + 1] = cy; o1[m * 3 + 2] = cz;
        (o1 + MCENT * 3)[m] = (float)bcl;
    }
    __syncthreads();

    // ---- phase A: cooperative scan, float4 loads, each point tested vs 4 centers ----
    bool uni = (bcls[0] == bcls[1]) && (bcls[1] == bcls[2]) && (bcls[2] == bcls[3]);
    if (uni) {
        float4 cA = cen[0], cB = cen[1], cC = cen[2], cD = cen[3];
        int jb = bcls[0] << 12;
        const float4* pb4 = (const float4*)(pos + (size_t)jb * 3);

#define TEST1(CEN, CI, SP, PX, PY, PZ, J) { \
    float dt = __fadd_rn(__fadd_rn(__fmul_rn(CEN.x, PX), __fmul_rn(CEN.y, PY)), __fmul_rn(CEN.z, PZ)); \
    float d2 = __fsub_rn(__fadd_rn(CEN.w, SP), __fmul_rn(2.0f, dt)); \
    if (d2 <= R2) push_hit(CI, d2, J, acnt, lists); }
#define TESTP(PX, PY, PZ, J) { \
    float sp = __fadd_rn(__fadd_rn(__fmul_rn(PX, PX), __fmul_rn(PY, PY)), __fmul_rn(PZ, PZ)); \
    TEST1(cA, 0, sp, PX, PY, PZ, J) \
    TEST1(cB, 1, sp, PX, PY, PZ, J) \
    TEST1(cC, 2, sp, PX, PY, PZ, J) \
    TEST1(cD, 3, sp, PX, PY, PZ, J) }

        #pragma unroll
        for (int it = 0; it < 4; it++) {
            int tq = it * 256 + tid;                   // quad-point index 0..1023
            float4 q0 = pb4[tq * 3], q1 = pb4[tq * 3 + 1], q2 = pb4[tq * 3 + 2];
            int j0 = jb + tq * 4;
            TESTP(q0.x, q0.y, q0.z, j0)
            TESTP(q0.w, q1.x, q1.y, j0 + 1)
            TESTP(q1.z, q1.w, q2.x, j0 + 2)
            TESTP(q2.y, q2.z, q2.w, j0 + 3)
        }
#undef TESTP
#undef TEST1
    } else {
        // rare mixed-cloud block: per-wave scan of own cloud from global
        for (int t = l; t < PCLOUD; t += 64) {
            int j = base + t;
            float px = pos[j * 3], py = pos[j * 3 + 1], pz = pos[j * 3 + 2];
            float sp = __fadd_rn(__fadd_rn(__fmul_rn(px, px), __fmul_rn(py, py)), __fmul_rn(pz, pz));
            float dt = __fadd_rn(__fadd_rn(__fmul_rn(cx, px), __fmul_rn(cy, py)), __fmul_rn(cz, pz));
            float d2 = __fsub_rn(__fadd_rn(sc, sp), __fmul_rn(2.0f, dt));
            if (d2 <= R2) push_hit(w, d2, j, acnt, lists);
        }
    }
    __syncthreads();   // cross-wave list visibility

    int c = acnt[w];
    int nsel = c < KNBR ? c : KNBR;
    u64* mylist = lists + w * CAP;

    // ---- phase B: select the 32 smallest (d2,idx) keys (set only; order free) ----
    int selj = -1;
    if (c <= KNBR) {
        if (l < c) selj = (int)(u32)mylist[l];
    } else if (c <= CAP) {
        u64 kk[7];
        int bk[7];
        if (l < 32) hist[w * 32 + l] = 0;              // same-wave LDS: ordered
        #pragma unroll
        for (int i = 0; i < 7; i++) kk[i] = (l + i * 64 < c) ? mylist[l + i * 64] : ~0ull;
        #pragma unroll
        for (int i = 0; i < 7; i++) {                  // build d2 histogram (this wave only)
            bk[i] = 32;
            if (kk[i] != ~0ull) {
                bk[i] = key_bucket(kk[i]);
                atomicAdd(&hist[w * 32 + bk[i]], 1u);
            }
        }
        int hv = (l < 32) ? (int)hist[w * 32 + l] : 0; // atomics above are same-wave: ordered
        #pragma unroll
        for (int off = 1; off <= 16; off <<= 1) {   // inclusive scan, lanes 0..31
            int o = __shfl_up(hv, off);
            if (l >= off) hv += o;
        }
        u64 ge = __ballot((l < 32) && (hv >= KNBR));
        int B = __ffsll((unsigned long long)ge) - 1;        // threshold bucket
        int S = (B == 0) ? 0 : __shfl(hv, B - 1);           // count strictly below B
        #pragma unroll
        for (int i = 0; i < 7; i++) {                       // bulk-select below B
            if (kk[i] != ~0ull) {
                if (bk[i] < B) { int p = atomicAdd(&cnt2[w], 1); nbrl[w * 32 + p] = (int)(u32)kk[i]; }
                if (bk[i] != B) kk[i] = ~0ull;              // keep only bucket-B keys
            }
        }
        int need = KNBR - S;                                // expected ~4-12 rounds
        u64 last = 0;
        for (int r = 0; r < need; r++) {
            u64 mn = ~0ull;
            #pragma unroll
            for (int i = 0; i < 7; i++) if (kk[i] > last && kk[i] < mn) mn = kk[i];
            mn = wave_min_u64(mn);
            if (l == 0) nbrl[w * 32 + S + r] = (int)(u32)mn;
            last = mn;
        }
        if (l < KNBR) selj = nbrl[w * 32 + l];
    } else {
        // overflow fallback (never taken for uniform data): streaming 32-round argmin
        u64 last = 0;
        for (int r = 0; r < KNBR; r++) {
            u64 mn = ~0ull;
            for (int t = l; t < PCLOUD; t += 64) {
                int j = base + t;
                float px = pos[j * 3], py = pos[j * 3 + 1], pz = pos[j * 3 + 2];
                float sp = __fadd_rn(__fadd_rn(__fmul_rn(px, px), __fmul_rn(py, py)), __fmul_rn(pz, pz));
                float dt = __fadd_rn(__fadd_rn(__fmul_rn(cx, px), __fmul_rn(cy, py)), __fmul_rn(cz, pz));
                float d2 = __fsub_rn(__fadd_rn(sc, sp), __fmul_rn(2.0f, dt));
                if (d2 <= R2) { u64 kf = d2key(d2, j); if (kf > last && kf < mn) mn = kf; }
            }
            mn = wave_min_u64(mn);
            if (l == r) selj = (int)(u32)mn;
            last = mn;
        }
    }
    __syncthreads();   // LAST barrier: lists/hist dead; sA becomes the (wave-private) A-tile

    // ---- gather 32 feat rows per wave (XOR 16B-chunk swizzle); rows are wave-private,
    //      and every LDS access below stays within this wave's rows => no more barriers.
    {
        int h = l & 1, rl = l >> 1;
        int row = w * 32 + rl;
        int j = __shfl(selj, rl);
        int xv = row & 7;
        uint4* dst = sA4 + row * 16;
        uint4 z; z.x = z.y = z.z = z.w = 0;
        if (j >= 0) {
            const float4* sx = (const float4*)(x + (size_t)j * DIN);
            int c0lo = h ? 6 : 0, c0hi = h ? 8 : 6;
            for (int c0 = c0lo; c0 < c0hi; c0++) {
                float4 f0 = sx[c0 * 2], f1 = sx[c0 * 2 + 1];
                uint4 pv;
                pv.x = cvtpk(f0.x, f0.y); pv.y = cvtpk(f0.z, f0.w);
                pv.z = cvtpk(f1.x, f1.y); pv.w = cvtpk(f1.z, f1.w);
                dst[c0 ^ xv] = pv;
            }
            if (h == 1) {
                float rx = pos[j * 3] - cx, ry = pos[j * 3 + 1] - cy, rz = pos[j * 3 + 2] - cz;
                uint4 rc; rc.x = cvtpk(rx, ry); rc.y = cvtpk(rz, 0.0f); rc.z = 0; rc.w = 0;
                dst[8 ^ xv] = rc;
                dst[9 ^ xv] = z; dst[10 ^ xv] = z; dst[11 ^ xv] = z;
            }
        } else {
            int c0lo = h ? 6 : 0, c0hi = h ? 12 : 6;
            for (int c0 = c0lo; c0 < c0hi; c0++) dst[c0 ^ xv] = z;
        }
    }

    int m16 = l & 15, quad = l >> 4;
    int r0 = w * 32;
    const floatx4 vzero = {0.f, 0.f, 0.f, 0.f};

#define LDB(BLK, CB, W, RS, COL, KR) \
    (WS ? ldB_ws(ws4, (BLK), (CB), m16) : ldB_fb((W), (RS), (COL), (CB), (KR)))

    // ==== GEMM1: h1 = relu(feat @ W1 + b1), K=96, swapped operands, 8 x 16-col groups ====
    {
        bf16x8 a1[3][2];
        #pragma unroll
        for (int ki = 0; ki < 3; ki++)
            #pragma unroll
            for (int t = 0; t < 2; t++) {
                int row = r0 + t * 16 + m16;
                a1[ki][t] = __builtin_bit_cast(bf16x8, sA4[row * 16 + ((ki * 4 + quad) ^ (row & 7))]);
            }
        uint4 bc[3];
        #pragma unroll
        for (int ki = 0; ki < 3; ki++) bc[ki] = LDB(0, ki * 4 + quad, W1, 128, m16, 67);
        #pragma unroll
        for (int s = 0; s < 8; s++) {
            uint4 bn[3];
            if (s < 7) {
                #pragma unroll
                for (int ki = 0; ki < 3; ki++)
                    bn[ki] = LDB(s + 1, ki * 4 + quad, W1, 128, (s + 1) * 16 + m16, 67);
            }
            floatx4 acc[2] = {vzero, vzero};
            __builtin_amdgcn_s_setprio(1);
            #pragma unroll
            for (int ki = 0; ki < 3; ki++) {
                bf16x8 b = __builtin_bit_cast(bf16x8, bc[ki]);
                #pragma unroll
                for (int t = 0; t < 2; t++)
                    acc[t] = __builtin_amdgcn_mfma_f32_16x16x32_bf16(b, a1[ki][t], acc[t], 0, 0, 0);
            }
            __builtin_amdgcn_s_setprio(0);
            float4 bb = ((const float4*)b1)[s * 4 + quad];  // cols s*16+quad*4..+3
            #pragma unroll
            for (int t = 0; t < 2; t++) {
                int rr = r0 + t * 16 + m16;
                uint2 pv;
                pv.x = cvtpk(fmaxf(acc[t][0] + bb.x, 0.f), fmaxf(acc[t][1] + bb.y, 0.f));
                pv.y = cvtpk(fmaxf(acc[t][2] + bb.z, 0.f), fmaxf(acc[t][3] + bb.w, 0.f));
                *(uint2*)(smem + rr * 256 + (((s * 2 + (quad >> 1)) ^ (rr & 7)) << 4) + ((quad & 1) << 3)) = pv;
            }
            if (s < 7) {
                #pragma unroll
                for (int ki = 0; ki < 3; ki++) bc[ki] = bn[ki];
            }
        }
    }

    // ==== GEMM2: h2 = relu(h1 @ W2 + b2), K=128, swapped operands, 8 x 16-col groups ====
    {
        bf16x8 a2[4][2];
        #pragma unroll
        for (int ki = 0; ki < 4; ki++)
            #pragma unroll
            for (int t = 0; t < 2; t++) {
                int row = r0 + t * 16 + m16;
                a2[ki][t] = __builtin_bit_cast(bf16x8, sA4[row * 16 + ((ki * 4 + quad) ^ (row & 7))]);
            }
        uint4 bc[4];
        #pragma unroll
        for (int ki = 0; ki < 4; ki++) bc[ki] = LDB(8, ki * 4 + quad, W2, 128, m16, 128);
        #pragma unroll
        for (int s = 0; s < 8; s++) {
            uint4 bn[4];
            if (s < 7) {
                #pragma unroll
                for (int ki = 0; ki < 4; ki++)
                    bn[ki] = LDB(9 + s, ki * 4 + quad, W2, 128, (s + 1) * 16 + m16, 128);
            }
            floatx4 acc[2] = {vzero, vzero};
            __builtin_amdgcn_s_setprio(1);
            #pragma unroll
            for (int ki = 0; ki < 4; ki++) {
                bf16x8 b = __builtin_bit_cast(bf16x8, bc[ki]);
                #pragma unroll
                for (int t = 0; t < 2; t++)
                    acc[t] = __builtin_amdgcn_mfma_f32_16x16x32_bf16(b, a2[ki][t], acc[t], 0, 0, 0);
            }
            __builtin_amdgcn_s_setprio(0);
            float4 bb = ((const float4*)b2)[s * 4 + quad];
            #pragma unroll
            for (int t = 0; t < 2; t++) {
                int rr = r0 + t * 16 + m16;
                uint2 pv;
                pv.x = cvtpk(fmaxf(acc[t][0] + bb.x, 0.f), fmaxf(acc[t][1] + bb.y, 0.f));
                pv.y = cvtpk(fmaxf(acc[t][2] + bb.z, 0.f), fmaxf(acc[t][3] + bb.w, 0.f));
                *(uint2*)(smem + rr * 256 + (((s * 2 + (quad >> 1)) ^ (rr & 7)) << 4) + ((quad & 1) << 3)) = pv;
            }
            if (s < 7) {
                #pragma unroll
                for (int ki = 0; ki < 4; ki++) bc[ki] = bn[ki];
            }
        }
    }

    // ==== GEMM3: out = maxpool(relu(h2 @ W3 + b3)), K=128, N=256, 16 x 16-col groups ====
    {
        bf16x8 a3[4][2];
        #pragma unroll
        for (int ki = 0; ki < 4; ki++)
            #pragma unroll
            for (int t = 0; t < 2; t++) {
                int row = r0 + t * 16 + m16;
                a3[ki][t] = __builtin_bit_cast(bf16x8, sA4[row * 16 + ((ki * 4 + quad) ^ (row & 7))]);
            }
        uint4 bc[4];
        #pragma unroll
        for (int ki = 0; ki < 4; ki++) bc[ki] = LDB(16, ki * 4 + quad, W3, 256, m16, 128);
        #pragma unroll
        for (int s = 0; s < 16; s++) {
            uint4 bn[4];
            if (s < 15) {
                #pragma unroll
                for (int ki = 0; ki < 4; ki++)
                    bn[ki] = LDB(17 + s, ki * 4 + quad, W3, 256, (s + 1) * 16 + m16, 128);
            }
            floatx4 acc[2] = {vzero, vzero};
            __builtin_amdgcn_s_setprio(1);
            #pragma unroll
            for (int ki = 0; ki < 4; ki++) {
                bf16x8 b = __builtin_bit_cast(bf16x8, bc[ki]);
                #pragma unroll
                for (int t = 0; t < 2; t++)
                    acc[t] = __builtin_amdgcn_mfma_f32_16x16x32_bf16(a3[ki][t], b, acc[t], 0, 0, 0);
            }
            __builtin_amdgcn_s_setprio(0);
            int col = s * 16 + m16;
            float bias = b3[col];
            float mv = 0.0f;   // post-ReLU max over >=1 valid nbr is >= 0
            #pragma unroll
            for (int t = 0; t < 2; t++)
                #pragma unroll
                for (int i = 0; i < 4; i++) {
                    int k = t * 16 + quad * 4 + i;
                    float v = fmaxf(acc[t][i] + bias, 0.0f);
                    if (k < nsel) mv = fmaxf(mv, v);
                }
            mv = fmaxf(mv, __shfl_xor(mv, 16));
            mv = fmaxf(mv, __shfl_xor(mv, 32));
            if (quad == 0) out[(m0 + w) * 256 + col] = mv;
            if (s < 15) {
                #pragma unroll
                for (int ki = 0; ki < 4; ki++) bc[ki] = bn[ki];
            }
        }
    }
#undef LDB
}

extern "C" void kernel_launch(void* const* d_in, const int* in_sizes, int n_in,
                              void* d_out, int out_size, void* d_ws, size_t ws_size,
                              hipStream_t stream) {
    const float* x     = (const float*)d_in[0];
    const float* pos   = (const float*)d_in[1];
    const int*   batch = (const int*)d_in[2];
    const int*   idx   = (const int*)d_in[3];
    const float* W1    = (const float*)d_in[4];
    const float* b1    = (const float*)d_in[5];
    const float* W2    = (const float*)d_in[6];
    const float* b2    = (const float*)d_in[7];
    const float* W3    = (const float*)d_in[8];
    const float* b3    = (const float*)d_in[9];
    float* out = (float*)d_out;
    uint4* ws4 = (uint4*)d_ws;

    if (ws_size >= 131072) {
        hipLaunchKernelGGL(prep_kernel, dim3(32), dim3(256), 0, stream, W1, W2, W3, ws4);
        hipLaunchKernelGGL((sa_kernel<true>), dim3(MCENT / 4), dim3(256), 0, stream,
                           x, pos, batch, idx, W1, b1, W2, b2, W3, b3, ws4, out);
    } else {
        hipLaunchKernelGGL((sa_kernel<false>), dim3(MCENT / 4), dim3(256), 0, stream,
                           x, pos, batch, idx, W1, b1, W2, b2, W3, b3, ws4, out);
    }
}

// Round 6
// 162.252 us; speedup vs baseline: 1.0495x; 1.0087x over previous
//
#include <hip/hip_runtime.h>

// SAModule (PointNet++ SA), fused f32-input kernel. R11:
//  - R10 post-mortem: removing all barriers+staging was ~flat (94us) => latency on
//    serial chains, not issue bandwidth, dominates. Three exposed chains fixed:
//    * gather: runtime-bound loop serialized 6 dependent L2 loads -> h-branched
//      compile-time unroll, all x loads issued at once
//    * phase B: linear d2 buckets put ~all candidates in the threshold bucket ->
//      density-equalized monotone map b=32*t*sqrt(t) (t=d2/R2) => 1-4 argmin rounds
//    * GEMMs: 1-deep b-frag prefetch < L2 latency -> 2-deep even/odd register sets
//      (static indexing), prefetch issued right after the consuming MFMA cluster

typedef unsigned short u16;
typedef unsigned int u32;
typedef unsigned long long u64;
typedef __bf16 bf16x8 __attribute__((ext_vector_type(8)));
typedef float floatx4 __attribute__((ext_vector_type(4)));

#define PCLOUD 4096
#define DIN    64
#define MCENT  8192
#define KNBR   32
#define CAP    448

// smem map (32768 B): sA = 128 rows x 256B. phase A/B overlay (dead before gather):
#define OFF_LIST  0        // u64[4][CAP] = 14336
#define OFF_HIST  14336    // u32[4][32]  = 512
#define OFF_NBRL  14848    // int[4][32]  = 512
#define OFF_CNT   15360    // int[4] acnt | int[4] cnt2
#define OFF_CEN   15392    // float4[4] centers (x,y,z,|c|^2)
#define OFF_BCL   15456    // int[4] cloud ids

__device__ inline u16 f2bf(float f) {          // RNE, no scrub (inputs finite)
    u32 b = __float_as_uint(f);
    b += 0x7fffu + ((b >> 16) & 1u);
    return (u16)(b >> 16);
}
__device__ inline u32 cvtpk(float a, float b) {  // packed {bf16(a), bf16(b)<<16}, RNE
    u32 r;
    asm("v_cvt_pk_bf16_f32 %0, %1, %2" : "=v"(r) : "v"(a), "v"(b));
    return r;
}
__device__ inline u64 wave_min_u64(u64 v) {
    #pragma unroll
    for (int off = 32; off; off >>= 1) {
        u64 o = __shfl_xor((unsigned long long)v, off);
        if (o < v) v = o;
    }
    return v;
}
__device__ inline u64 d2key(float d2, int j) {
    u32 u = __float_as_uint(d2);
    u = (u & 0x80000000u) ? ~u : (u | 0x80000000u);   // order-preserving map
    return ((u64)u << 32) | (u32)j;
}
// density-equalized bucket: uniform points => count/bucket ~ const. Monotone in d2.
__device__ inline int key_bucket(u64 k) {
    u32 hi = (u32)(k >> 32);
    if (hi < 0x80000000u) return 0;                    // d2 <= -0
    float d2 = __uint_as_float(hi & 0x7fffffffu);
    float t = d2 * 25.0f;                              // d2/R2, [0,1]
    float b = 32.0f * t * __builtin_sqrtf(t);          // 32 * t^1.5
    int bi = (int)b;
    return bi > 31 ? 31 : (bi < 0 ? 0 : bi);
}

// ---- prep: weights -> bf16 B-fragment images in ws (consumed directly from L2) ----
// 32 contiguous 4KB blocks of 16 cols each: blk 0..7 = W1, 8..15 = W2, 16..31 = W3.
// blk layout (256 uint4): chunk[n*16 + (kc^(n&7))] = {bf16 W[kc*8+j][col0+n], j=0..7}
__global__ void prep_kernel(const float* __restrict__ W1, const float* __restrict__ W2,
                            const float* __restrict__ W3, uint4* __restrict__ ws) {
    int t = blockIdx.x * 256 + threadIdx.x;   // 0..8191
    int g = t >> 11, r = t & 2047;
    int n = r >> 4, kc = r & 15;
    const float* W; int rs, n0, krows;
    if (g == 0)      { W = W1; rs = 128; n0 = 0;   krows = 67;  }
    else if (g == 1) { W = W2; rs = 128; n0 = 0;   krows = 128; }
    else if (g == 2) { W = W3; rs = 256; n0 = 0;   krows = 128; }
    else             { W = W3; rs = 256; n0 = 128; krows = 128; }
    u16 e[8];
    #pragma unroll
    for (int j = 0; j < 8; j++) {
        int k = kc * 8 + j;
        e[j] = (k < krows) ? f2bf(W[(size_t)k * rs + n0 + n]) : (u16)0;
    }
    ws[(g << 11) + (n << 4) + (kc ^ (n & 7))] = *(const uint4*)e;
}

// One B-fragment (8 bf16 of col `col0+m16`, k-rows cb*8..cb*8+7), straight from ws/L2.
__device__ __forceinline__ uint4 ldB_ws(const uint4* __restrict__ ws4, int blk, int cb, int m16) {
    return ws4[blk * 256 + (m16 << 4) + (cb ^ (m16 & 7))];
}
// Workspace-less fallback: gather the column from W in f32 and pack (correctness path).
__device__ __forceinline__ uint4 ldB_fb(const float* __restrict__ W, int rs, int col,
                                        int cb, int krows) {
    u16 e[8];
    #pragma unroll
    for (int j = 0; j < 8; j++) {
        int k = cb * 8 + j;
        e[j] = (k < krows) ? f2bf(W[(size_t)k * rs + col]) : (u16)0;
    }
    return *(const uint4*)e;
}

__device__ __forceinline__ void push_hit(int c, float d2, int j,
                                         int* acnt, u64* lists) {
    int p = atomicAdd(&acnt[c], 1);
    if (p < CAP) lists[c * CAP + p] = d2key(d2, j);
}

template <bool WS>
__global__ __launch_bounds__(256, 4) void sa_kernel(
    const float* __restrict__ x, const float* __restrict__ pos,
    const int* __restrict__ batch, const int* __restrict__ idx,
    const float* __restrict__ W1, const float* __restrict__ b1,
    const float* __restrict__ W2, const float* __restrict__ b2,
    const float* __restrict__ W3, const float* __restrict__ b3,
    const uint4* __restrict__ ws4, float* __restrict__ out) {
    __shared__ __align__(16) char smem[32768];
    u64*  lists = (u64*)(smem + OFF_LIST);
    u32*  hist  = (u32*)(smem + OFF_HIST);
    int*  nbrl  = (int*)(smem + OFF_NBRL);
    int*  acnt  = (int*)(smem + OFF_CNT);
    int*  cnt2  = (int*)(smem + OFF_CNT + 16);
    float4* cen = (float4*)(smem + OFF_CEN);
    int*  bcls  = (int*)(smem + OFF_BCL);
    uint4* sA4  = (uint4*)smem;

    int tid = threadIdx.x, w = tid >> 6, l = tid & 63;
    int bid = blockIdx.x;
    int m0 = ((bid & 7) << 10) + ((bid >> 3) << 2);   // XCD-friendly: bid%8 ~ cloud
    int m = m0 + w;
    int ic = idx[m] & (8 * PCLOUD - 1);
    float cx = pos[ic * 3], cy = pos[ic * 3 + 1], cz = pos[ic * 3 + 2];
    float sc = __fadd_rn(__fadd_rn(__fmul_rn(cx, cx), __fmul_rn(cy, cy)), __fmul_rn(cz, cz));
    int bcl = batch[ic] & 7;
    int base = bcl << 12;
    const float R2 = 0.04f;

    if (l == 0) { cen[w] = make_float4(cx, cy, cz, sc); bcls[w] = bcl; }
    if (tid < 4) { acnt[tid] = 0; cnt2[tid] = 0; }
    if (l == 1) {
        float* o1 = out + MCENT * 256;
        o1[m * 3] = cx; o1[m * 3 + 1] = cy; o1[m * 3 + 2] = cz;
        (o1 + MCENT * 3)[m] = (float)bcl;
    }
    __syncthreads();

    // ---- phase A: cooperative scan, float4 loads, each point tested vs 4 centers ----
    bool uni = (bcls[0] == bcls[1]) && (bcls[1] == bcls[2]) && (bcls[2] == bcls[3]);
    if (uni) {
        float4 cA = cen[0], cB = cen[1], cC = cen[2], cD = cen[3];
        int jb = bcls[0] << 12;
        const float4* pb4 = (const float4*)(pos + (size_t)jb * 3);

#define TEST1(CEN, CI, SP, PX, PY, PZ, J) { \
    float dt = __fadd_rn(__fadd_rn(__fmul_rn(CEN.x, PX), __fmul_rn(CEN.y, PY)), __fmul_rn(CEN.z, PZ)); \
    float d2 = __fsub_rn(__fadd_rn(CEN.w, SP), __fmul_rn(2.0f, dt)); \
    if (d2 <= R2) push_hit(CI, d2, J, acnt, lists); }
#define TESTP(PX, PY, PZ, J) { \
    float sp = __fadd_rn(__fadd_rn(__fmul_rn(PX, PX), __fmul_rn(PY, PY)), __fmul_rn(PZ, PZ)); \
    TEST1(cA, 0, sp, PX, PY, PZ, J) \
    TEST1(cB, 1, sp, PX, PY, PZ, J) \
    TEST1(cC, 2, sp, PX, PY, PZ, J) \
    TEST1(cD, 3, sp, PX, PY, PZ, J) }

        #pragma unroll
        for (int it = 0; it < 4; it++) {
            int tq = it * 256 + tid;                   // quad-point index 0..1023
            float4 q0 = pb4[tq * 3], q1 = pb4[tq * 3 + 1], q2 = pb4[tq * 3 + 2];
            int j0 = jb + tq * 4;
            TESTP(q0.x, q0.y, q0.z, j0)
            TESTP(q0.w, q1.x, q1.y, j0 + 1)
            TESTP(q1.z, q1.w, q2.x, j0 + 2)
            TESTP(q2.y, q2.z, q2.w, j0 + 3)
        }
#undef TESTP
#undef TEST1
    } else {
        // rare mixed-cloud block: per-wave scan of own cloud from global
        for (int t = l; t < PCLOUD; t += 64) {
            int j = base + t;
            float px = pos[j * 3], py = pos[j * 3 + 1], pz = pos[j * 3 + 2];
            float sp = __fadd_rn(__fadd_rn(__fmul_rn(px, px), __fmul_rn(py, py)), __fmul_rn(pz, pz));
            float dt = __fadd_rn(__fadd_rn(__fmul_rn(cx, px), __fmul_rn(cy, py)), __fmul_rn(cz, pz));
            float d2 = __fsub_rn(__fadd_rn(sc, sp), __fmul_rn(2.0f, dt));
            if (d2 <= R2) push_hit(w, d2, j, acnt, lists);
        }
    }
    __syncthreads();   // cross-wave list visibility

    int c = acnt[w];
    int nsel = c < KNBR ? c : KNBR;
    u64* mylist = lists + w * CAP;

    // ---- phase B: select the 32 smallest (d2,idx) keys (set only; order free) ----
    int selj = -1;
    if (c <= KNBR) {
        if (l < c) selj = (int)(u32)mylist[l];
    } else if (c <= CAP) {
        u64 kk[7];
        int bk[7];
        if (l < 32) hist[w * 32 + l] = 0;              // same-wave LDS: ordered
        #pragma unroll
        for (int i = 0; i < 7; i++) kk[i] = (l + i * 64 < c) ? mylist[l + i * 64] : ~0ull;
        #pragma unroll
        for (int i = 0; i < 7; i++) {                  // build d2 histogram (this wave only)
            bk[i] = 32;
            if (kk[i] != ~0ull) {
                bk[i] = key_bucket(kk[i]);
                atomicAdd(&hist[w * 32 + bk[i]], 1u);
            }
        }
        int hv = (l < 32) ? (int)hist[w * 32 + l] : 0; // atomics above are same-wave: ordered
        #pragma unroll
        for (int off = 1; off <= 16; off <<= 1) {   // inclusive scan, lanes 0..31
            int o = __shfl_up(hv, off);
            if (l >= off) hv += o;
        }
        u64 ge = __ballot((l < 32) && (hv >= KNBR));
        int B = __ffsll((unsigned long long)ge) - 1;        // threshold bucket
        int S = (B == 0) ? 0 : __shfl(hv, B - 1);           // count strictly below B
        #pragma unroll
        for (int i = 0; i < 7; i++) {                       // bulk-select below B
            if (kk[i] != ~0ull) {
                if (bk[i] < B) { int p = atomicAdd(&cnt2[w], 1); nbrl[w * 32 + p] = (int)(u32)kk[i]; }
                if (bk[i] != B) kk[i] = ~0ull;              // keep only bucket-B keys
            }
        }
        int need = KNBR - S;                                // equalized buckets: ~1-4 rounds
        u64 last = 0;
        for (int r = 0; r < need; r++) {
            u64 mn = ~0ull;
            #pragma unroll
            for (int i = 0; i < 7; i++) if (kk[i] > last && kk[i] < mn) mn = kk[i];
            mn = wave_min_u64(mn);
            if (l == 0) nbrl[w * 32 + S + r] = (int)(u32)mn;
            last = mn;
        }
        if (l < KNBR) selj = nbrl[w * 32 + l];
    } else {
        // overflow fallback (never taken for uniform data): streaming 32-round argmin
        u64 last = 0;
        for (int r = 0; r < KNBR; r++) {
            u64 mn = ~0ull;
            for (int t = l; t < PCLOUD; t += 64) {
                int j = base + t;
                float px = pos[j * 3], py = pos[j * 3 + 1], pz = pos[j * 3 + 2];
                float sp = __fadd_rn(__fadd_rn(__fmul_rn(px, px), __fmul_rn(py, py)), __fmul_rn(pz, pz));
                float dt = __fadd_rn(__fadd_rn(__fmul_rn(cx, px), __fmul_rn(cy, py)), __fmul_rn(cz, pz));
                float d2 = __fsub_rn(__fadd_rn(sc, sp), __fmul_rn(2.0f, dt));
                if (d2 <= R2) { u64 kf = d2key(d2, j); if (kf > last && kf < mn) mn = kf; }
            }
            mn = wave_min_u64(mn);
            if (l == r) selj = (int)(u32)mn;
            last = mn;
        }
    }
    __syncthreads();   // LAST barrier: lists/hist dead; sA becomes the (wave-private) A-tile

    // ---- gather 32 feat rows per wave (XOR 16B-chunk swizzle); rows are wave-private.
    //      h-branched compile-time unroll: all x loads issue together (no serial chain).
    {
        int h = l & 1, rl = l >> 1;
        int row = w * 32 + rl;
        int j = __shfl(selj, rl);
        int xv = row & 7;
        uint4* dst = sA4 + row * 16;
        uint4 z; z.x = z.y = z.z = z.w = 0;
        if (j >= 0) {
            const float4* sx = (const float4*)(x + (size_t)j * DIN);
            if (h == 0) {
                float4 f[12];
                #pragma unroll
                for (int i = 0; i < 12; i++) f[i] = sx[i];
                #pragma unroll
                for (int c0 = 0; c0 < 6; c0++) {
                    uint4 pv;
                    pv.x = cvtpk(f[c0 * 2].x, f[c0 * 2].y);
                    pv.y = cvtpk(f[c0 * 2].z, f[c0 * 2].w);
                    pv.z = cvtpk(f[c0 * 2 + 1].x, f[c0 * 2 + 1].y);
                    pv.w = cvtpk(f[c0 * 2 + 1].z, f[c0 * 2 + 1].w);
                    dst[c0 ^ xv] = pv;
                }
            } else {
                float4 f[4];
                #pragma unroll
                for (int i = 0; i < 4; i++) f[i] = sx[12 + i];
                float rx = pos[j * 3] - cx, ry = pos[j * 3 + 1] - cy, rz = pos[j * 3 + 2] - cz;
                #pragma unroll
                for (int c0 = 0; c0 < 2; c0++) {
                    uint4 pv;
                    pv.x = cvtpk(f[c0 * 2].x, f[c0 * 2].y);
                    pv.y = cvtpk(f[c0 * 2].z, f[c0 * 2].w);
                    pv.z = cvtpk(f[c0 * 2 + 1].x, f[c0 * 2 + 1].y);
                    pv.w = cvtpk(f[c0 * 2 + 1].z, f[c0 * 2 + 1].w);
                    dst[(6 + c0) ^ xv] = pv;
                }
                uint4 rc; rc.x = cvtpk(rx, ry); rc.y = cvtpk(rz, 0.0f); rc.z = 0; rc.w = 0;
                dst[8 ^ xv] = rc;
                dst[9 ^ xv] = z; dst[10 ^ xv] = z; dst[11 ^ xv] = z;
            }
        } else {
            if (h == 0) {
                #pragma unroll
                for (int c0 = 0; c0 < 6; c0++) dst[c0 ^ xv] = z;
            } else {
                #pragma unroll
                for (int c0 = 6; c0 < 12; c0++) dst[c0 ^ xv] = z;
            }
        }
    }

    int m16 = l & 15, quad = l >> 4;
    int r0 = w * 32;
    const floatx4 vzero = {0.f, 0.f, 0.f, 0.f};

#define LDB(BLK, CB, W, RS, COL, KR) \
    (WS ? ldB_ws(ws4, (BLK), (CB), m16) : ldB_fb((W), (RS), (COL), (CB), (KR)))

// h-epilogue for GEMM1/2: relu(acc+bias) -> bf16 pair writes into swizzled sA rows
#define EPI12(BPTR, S, ACC) { \
    float4 bb = ((const float4*)(BPTR))[(S) * 4 + quad]; \
    _Pragma("unroll") \
    for (int t = 0; t < 2; t++) { \
        int rr = r0 + t * 16 + m16; \
        uint2 pv; \
        pv.x = cvtpk(fmaxf(ACC[t][0] + bb.x, 0.f), fmaxf(ACC[t][1] + bb.y, 0.f)); \
        pv.y = cvtpk(fmaxf(ACC[t][2] + bb.z, 0.f), fmaxf(ACC[t][3] + bb.w, 0.f)); \
        *(uint2*)(smem + rr * 256 + ((((S) * 2 + (quad >> 1)) ^ (rr & 7)) << 4) + ((quad & 1) << 3)) = pv; \
    } }

    // ==== GEMM1: h1 = relu(feat @ W1 + b1), K=96, swapped operands, 8 steps, 2-deep ====
    {
        bf16x8 a1[3][2];
        #pragma unroll
        for (int ki = 0; ki < 3; ki++)
            #pragma unroll
            for (int t = 0; t < 2; t++) {
                int row = r0 + t * 16 + m16;
                a1[ki][t] = __builtin_bit_cast(bf16x8, sA4[row * 16 + ((ki * 4 + quad) ^ (row & 7))]);
            }
        uint4 p0[3], p1[3];
        #pragma unroll
        for (int ki = 0; ki < 3; ki++) p0[ki] = LDB(0, ki * 4 + quad, W1, 128, m16, 67);
        #pragma unroll
        for (int ki = 0; ki < 3; ki++) p1[ki] = LDB(1, ki * 4 + quad, W1, 128, 16 + m16, 67);
        #pragma unroll
        for (int s = 0; s < 8; s += 2) {
            {
                floatx4 acc[2] = {vzero, vzero};
                __builtin_amdgcn_s_setprio(1);
                #pragma unroll
                for (int ki = 0; ki < 3; ki++) {
                    bf16x8 b = __builtin_bit_cast(bf16x8, p0[ki]);
                    #pragma unroll
                    for (int t = 0; t < 2; t++)
                        acc[t] = __builtin_amdgcn_mfma_f32_16x16x32_bf16(b, a1[ki][t], acc[t], 0, 0, 0);
                }
                __builtin_amdgcn_s_setprio(0);
                if (s + 2 < 8) {
                    #pragma unroll
                    for (int ki = 0; ki < 3; ki++)
                        p0[ki] = LDB(s + 2, ki * 4 + quad, W1, 128, (s + 2) * 16 + m16, 67);
                }
                EPI12(b1, s, acc);
            }
            {
                floatx4 acc[2] = {vzero, vzero};
                __builtin_amdgcn_s_setprio(1);
                #pragma unroll
                for (int ki = 0; ki < 3; ki++) {
                    bf16x8 b = __builtin_bit_cast(bf16x8, p1[ki]);
                    #pragma unroll
                    for (int t = 0; t < 2; t++)
                        acc[t] = __builtin_amdgcn_mfma_f32_16x16x32_bf16(b, a1[ki][t], acc[t], 0, 0, 0);
                }
                __builtin_amdgcn_s_setprio(0);
                if (s + 3 < 8) {
                    #pragma unroll
                    for (int ki = 0; ki < 3; ki++)
                        p1[ki] = LDB(s + 3, ki * 4 + quad, W1, 128, (s + 3) * 16 + m16, 67);
                }
                EPI12(b1, s + 1, acc);
            }
        }
    }

    // ==== GEMM2: h2 = relu(h1 @ W2 + b2), K=128, swapped operands, 8 steps, 2-deep ====
    {
        bf16x8 a2[4][2];
        #pragma unroll
        for (int ki = 0; ki < 4; ki++)
            #pragma unroll
            for (int t = 0; t < 2; t++) {
                int row = r0 + t * 16 + m16;
                a2[ki][t] = __builtin_bit_cast(bf16x8, sA4[row * 16 + ((ki * 4 + quad) ^ (row & 7))]);
            }
        uint4 p0[4], p1[4];
        #pragma unroll
        for (int ki = 0; ki < 4; ki++) p0[ki] = LDB(8, ki * 4 + quad, W2, 128, m16, 128);
        #pragma unroll
        for (int ki = 0; ki < 4; ki++) p1[ki] = LDB(9, ki * 4 + quad, W2, 128, 16 + m16, 128);
        #pragma unroll
        for (int s = 0; s < 8; s += 2) {
            {
                floatx4 acc[2] = {vzero, vzero};
                __builtin_amdgcn_s_setprio(1);
                #pragma unroll
                for (int ki = 0; ki < 4; ki++) {
                    bf16x8 b = __builtin_bit_cast(bf16x8, p0[ki]);
                    #pragma unroll
                    for (int t = 0; t < 2; t++)
                        acc[t] = __builtin_amdgcn_mfma_f32_16x16x32_bf16(b, a2[ki][t], acc[t], 0, 0, 0);
                }
                __builtin_amdgcn_s_setprio(0);
                if (s + 2 < 8) {
                    #pragma unroll
                    for (int ki = 0; ki < 4; ki++)
                        p0[ki] = LDB(8 + s + 2, ki * 4 + quad, W2, 128, (s + 2) * 16 + m16, 128);
                }
                EPI12(b2, s, acc);
            }
            {
                floatx4 acc[2] = {vzero, vzero};
                __builtin_amdgcn_s_setprio(1);
                #pragma unroll
                for (int ki = 0; ki < 4; ki++) {
                    bf16x8 b = __builtin_bit_cast(bf16x8, p1[ki]);
                    #pragma unroll
                    for (int t = 0; t < 2; t++)
                        acc[t] = __builtin_amdgcn_mfma_f32_16x16x32_bf16(b, a2[ki][t], acc[t], 0, 0, 0);
                }
                __builtin_amdgcn_s_setprio(0);
                if (s + 3 < 8) {
                    #pragma unroll
                    for (int ki = 0; ki < 4; ki++)
                        p1[ki] = LDB(8 + s + 3, ki * 4 + quad, W2, 128, (s + 3) * 16 + m16, 128);
                }
                EPI12(b2, s + 1, acc);
            }
        }
    }

// GEMM3 epilogue: masked max over this wave's 32 rows, reduce across quads, store
#define EPI3(S, ACC) { \
    int col = (S) * 16 + m16; \
    float bias = b3[col]; \
    float mv = 0.0f; \
    _Pragma("unroll") \
    for (int t = 0; t < 2; t++) \
        _Pragma("unroll") \
        for (int i = 0; i < 4; i++) { \
            int k = t * 16 + quad * 4 + i; \
            float v = fmaxf(ACC[t][i] + bias, 0.0f); \
            if (k < nsel) mv = fmaxf(mv, v); \
        } \
    mv = fmaxf(mv, __shfl_xor(mv, 16)); \
    mv = fmaxf(mv, __shfl_xor(mv, 32)); \
    if (quad == 0) out[(m0 + w) * 256 + col] = mv; }

    // ==== GEMM3: out = maxpool(relu(h2 @ W3 + b3)), K=128, N=256, 16 steps, 2-deep ====
    {
        bf16x8 a3[4][2];
        #pragma unroll
        for (int ki = 0; ki < 4; ki++)
            #pragma unroll
            for (int t = 0; t < 2; t++) {
                int row = r0 + t * 16 + m16;
                a3[ki][t] = __builtin_bit_cast(bf16x8, sA4[row * 16 + ((ki * 4 + quad) ^ (row & 7))]);
            }
        uint4 p0[4], p1[4];
        #pragma unroll
        for (int ki = 0; ki < 4; ki++) p0[ki] = LDB(16, ki * 4 + quad, W3, 256, m16, 128);
        #pragma unroll
        for (int ki = 0; ki < 4; ki++) p1[ki] = LDB(17, ki * 4 + quad, W3, 256, 16 + m16, 128);
        #pragma unroll
        for (int s = 0; s < 16; s += 2) {
            {
                floatx4 acc[2] = {vzero, vzero};
                __builtin_amdgcn_s_setprio(1);
                #pragma unroll
                for (int ki = 0; ki < 4; ki++) {
                    bf16x8 b = __builtin_bit_cast(bf16x8, p0[ki]);
                    #pragma unroll
                    for (int t = 0; t < 2; t++)
                        acc[t] = __builtin_amdgcn_mfma_f32_16x16x32_bf16(a3[ki][t], b, acc[t], 0, 0, 0);
                }
                __builtin_amdgcn_s_setprio(0);
                if (s + 2 < 16) {
                    #pragma unroll
                    for (int ki = 0; ki < 4; ki++)
                        p0[ki] = LDB(16 + s + 2, ki * 4 + quad, W3, 256, (s + 2) * 16 + m16, 128);
                }
                EPI3(s, acc);
            }
            {
                floatx4 acc[2] = {vzero, vzero};
                __builtin_amdgcn_s_setprio(1);
                #pragma unroll
                for (int ki = 0; ki < 4; ki++) {
                    bf16x8 b = __builtin_bit_cast(bf16x8, p1[ki]);
                    #pragma unroll
                    for (int t = 0; t < 2; t++)
                        acc[t] = __builtin_amdgcn_mfma_f32_16x16x32_bf16(a3[ki][t], b, acc[t], 0, 0, 0);
                }
                __builtin_amdgcn_s_setprio(0);
                if (s + 3 < 16) {
                    #pragma unroll
                    for (int ki = 0; ki < 4; ki++)
                        p1[ki] = LDB(16 + s + 3, ki * 4 + quad, W3, 256, (s + 3) * 16 + m16, 128);
                }
                EPI3(s + 1, acc);
            }
        }
    }
#undef LDB
#undef EPI12
#undef EPI3
}

extern "C" void kernel_launch(void* const* d_in, const int* in_sizes, int n_in,
                              void* d_out, int out_size, void* d_ws, size_t ws_size,
                              hipStream_t stream) {
    const float* x     = (const float*)d_in[0];
    const float* pos   = (const float*)d_in[1];
    const int*   batch = (const int*)d_in[2];
    const int*   idx   = (const int*)d_in[3];
    const float* W1    = (const float*)d_in[4];
    const float* b1    = (const float*)d_in[5];
    const float* W2    = (const float*)d_in[6];
    const float* b2    = (const float*)d_in[7];
    const float* W3    = (const float*)d_in[8];
    const float* b3    = (const float*)d_in[9];
    float* out = (float*)d_out;
    uint4* ws4 = (uint4*)d_ws;

    if (ws_size >= 131072) {
        hipLaunchKernelGGL(prep_kernel, dim3(32), dim3(256), 0, stream, W1, W2, W3, ws4);
        hipLaunchKernelGGL((sa_kernel<true>), dim3(MCENT / 4), dim3(256), 0, stream,
                           x, pos, batch, idx, W1, b1, W2, b2, W3, b3, ws4, out);
    } else {
        hipLaunchKernelGGL((sa_kernel<false>), dim3(MCENT / 4), dim3(256), 0, stream,
                           x, pos, batch, idx, W1, b1, W2, b2, W3, b3, ws4, out);
    }
}

// Round 7
// 161.200 us; speedup vs baseline: 1.0563x; 1.0065x over previous
//
#include <hip/hip_runtime.h>

// SAModule (PointNet++ SA), fused f32-input kernel. R12:
//  - R11 post-mortem: three different schedules all 91-97us; counters say VALU issue
//    (~6400 inst/wave) is the binding resource, occupancy capped at 16 waves/CU by the
//    irreducible 8KB/center h-tile. => cut VALU.
//  - R12 (single change vs R11): phase-A distance math FMA-contracted:
//    d2 = fma(-2cx,px, fma(-2cy,py, fma(-2cz,pz, sc+sp))), sp = fma(px,px, fma(py,py, pz*pz))
//    5 ops/center-test vs 10.5, ~-50% phase-A VALU. Safe: d2 rounding already differs
//    from the XLA reference; 32nd/33rd-neighbor gaps (~3e-4) dwarf FMA perturbation (~1e-7),
//    absmax has been selection-stable at the bf16 quantum for 6 rounds.

typedef unsigned short u16;
typedef unsigned int u32;
typedef unsigned long long u64;
typedef __bf16 bf16x8 __attribute__((ext_vector_type(8)));
typedef float floatx4 __attribute__((ext_vector_type(4)));

#define PCLOUD 4096
#define DIN    64
#define MCENT  8192
#define KNBR   32
#define CAP    448

// smem map (32768 B): sA = 128 rows x 256B. phase A/B overlay (dead before gather):
#define OFF_LIST  0        // u64[4][CAP] = 14336
#define OFF_HIST  14336    // u32[4][32]  = 512
#define OFF_NBRL  14848    // int[4][32]  = 512
#define OFF_CNT   15360    // int[4] acnt | int[4] cnt2
#define OFF_CEN   15392    // float4[4] centers (x,y,z,|c|^2)
#define OFF_BCL   15456    // int[4] cloud ids

__device__ inline u16 f2bf(float f) {          // RNE, no scrub (inputs finite)
    u32 b = __float_as_uint(f);
    b += 0x7fffu + ((b >> 16) & 1u);
    return (u16)(b >> 16);
}
__device__ inline u32 cvtpk(float a, float b) {  // packed {bf16(a), bf16(b)<<16}, RNE
    u32 r;
    asm("v_cvt_pk_bf16_f32 %0, %1, %2" : "=v"(r) : "v"(a), "v"(b));
    return r;
}
__device__ inline u64 wave_min_u64(u64 v) {
    #pragma unroll
    for (int off = 32; off; off >>= 1) {
        u64 o = __shfl_xor((unsigned long long)v, off);
        if (o < v) v = o;
    }
    return v;
}
__device__ inline u64 d2key(float d2, int j) {
    u32 u = __float_as_uint(d2);
    u = (u & 0x80000000u) ? ~u : (u | 0x80000000u);   // order-preserving map
    return ((u64)u << 32) | (u32)j;
}
// density-equalized bucket: uniform points => count/bucket ~ const. Monotone in d2.
__device__ inline int key_bucket(u64 k) {
    u32 hi = (u32)(k >> 32);
    if (hi < 0x80000000u) return 0;                    // d2 <= -0
    float d2 = __uint_as_float(hi & 0x7fffffffu);
    float t = d2 * 25.0f;                              // d2/R2, [0,1]
    float b = 32.0f * t * __builtin_sqrtf(t);          // 32 * t^1.5
    int bi = (int)b;
    return bi > 31 ? 31 : (bi < 0 ? 0 : bi);
}

// ---- prep: weights -> bf16 B-fragment images in ws (consumed directly from L2) ----
// 32 contiguous 4KB blocks of 16 cols each: blk 0..7 = W1, 8..15 = W2, 16..31 = W3.
// blk layout (256 uint4): chunk[n*16 + (kc^(n&7))] = {bf16 W[kc*8+j][col0+n], j=0..7}
__global__ void prep_kernel(const float* __restrict__ W1, const float* __restrict__ W2,
                            const float* __restrict__ W3, uint4* __restrict__ ws) {
    int t = blockIdx.x * 256 + threadIdx.x;   // 0..8191
    int g = t >> 11, r = t & 2047;
    int n = r >> 4, kc = r & 15;
    const float* W; int rs, n0, krows;
    if (g == 0)      { W = W1; rs = 128; n0 = 0;   krows = 67;  }
    else if (g == 1) { W = W2; rs = 128; n0 = 0;   krows = 128; }
    else if (g == 2) { W = W3; rs = 256; n0 = 0;   krows = 128; }
    else             { W = W3; rs = 256; n0 = 128; krows = 128; }
    u16 e[8];
    #pragma unroll
    for (int j = 0; j < 8; j++) {
        int k = kc * 8 + j;
        e[j] = (k < krows) ? f2bf(W[(size_t)k * rs + n0 + n]) : (u16)0;
    }
    ws[(g << 11) + (n << 4) + (kc ^ (n & 7))] = *(const uint4*)e;
}

// One B-fragment (8 bf16 of col `col0+m16`, k-rows cb*8..cb*8+7), straight from ws/L2.
__device__ __forceinline__ uint4 ldB_ws(const uint4* __restrict__ ws4, int blk, int cb, int m16) {
    return ws4[blk * 256 + (m16 << 4) + (cb ^ (m16 & 7))];
}
// Workspace-less fallback: gather the column from W in f32 and pack (correctness path).
__device__ __forceinline__ uint4 ldB_fb(const float* __restrict__ W, int rs, int col,
                                        int cb, int krows) {
    u16 e[8];
    #pragma unroll
    for (int j = 0; j < 8; j++) {
        int k = cb * 8 + j;
        e[j] = (k < krows) ? f2bf(W[(size_t)k * rs + col]) : (u16)0;
    }
    return *(const uint4*)e;
}

__device__ __forceinline__ void push_hit(int c, float d2, int j,
                                         int* acnt, u64* lists) {
    int p = atomicAdd(&acnt[c], 1);
    if (p < CAP) lists[c * CAP + p] = d2key(d2, j);
}

template <bool WS>
__global__ __launch_bounds__(256, 4) void sa_kernel(
    const float* __restrict__ x, const float* __restrict__ pos,
    const int* __restrict__ batch, const int* __restrict__ idx,
    const float* __restrict__ W1, const float* __restrict__ b1,
    const float* __restrict__ W2, const float* __restrict__ b2,
    const float* __restrict__ W3, const float* __restrict__ b3,
    const uint4* __restrict__ ws4, float* __restrict__ out) {
    __shared__ __align__(16) char smem[32768];
    u64*  lists = (u64*)(smem + OFF_LIST);
    u32*  hist  = (u32*)(smem + OFF_HIST);
    int*  nbrl  = (int*)(smem + OFF_NBRL);
    int*  acnt  = (int*)(smem + OFF_CNT);
    int*  cnt2  = (int*)(smem + OFF_CNT + 16);
    float4* cen = (float4*)(smem + OFF_CEN);
    int*  bcls  = (int*)(smem + OFF_BCL);
    uint4* sA4  = (uint4*)smem;

    int tid = threadIdx.x, w = tid >> 6, l = tid & 63;
    int bid = blockIdx.x;
    int m0 = ((bid & 7) << 10) + ((bid >> 3) << 2);   // XCD-friendly: bid%8 ~ cloud
    int m = m0 + w;
    int ic = idx[m] & (8 * PCLOUD - 1);
    float cx = pos[ic * 3], cy = pos[ic * 3 + 1], cz = pos[ic * 3 + 2];
    float sc = __fadd_rn(__fadd_rn(__fmul_rn(cx, cx), __fmul_rn(cy, cy)), __fmul_rn(cz, cz));
    int bcl = batch[ic] & 7;
    int base = bcl << 12;
    const float R2 = 0.04f;

    if (l == 0) { cen[w] = make_float4(cx, cy, cz, sc); bcls[w] = bcl; }
    if (tid < 4) { acnt[tid] = 0; cnt2[tid] = 0; }
    if (l == 1) {
        float* o1 = out + MCENT * 256;
        o1[m * 3] = cx; o1[m * 3 + 1] = cy; o1[m * 3 + 2] = cz;
        (o1 + MCENT * 3)[m] = (float)bcl;
    }
    __syncthreads();

    // ---- phase A: cooperative scan, float4 loads, FMA-contracted distance tests ----
    bool uni = (bcls[0] == bcls[1]) && (bcls[1] == bcls[2]) && (bcls[2] == bcls[3]);
    if (uni) {
        float4 cA = cen[0], cB = cen[1], cC = cen[2], cD = cen[3];
        // negated-doubled centers (exact *2): d2 = fma(nx,px, fma(ny,py, fma(nz,pz, sc+sp)))
        float nAx = -2.0f * cA.x, nAy = -2.0f * cA.y, nAz = -2.0f * cA.z;
        float nBx = -2.0f * cB.x, nBy = -2.0f * cB.y, nBz = -2.0f * cB.z;
        float nCx = -2.0f * cC.x, nCy = -2.0f * cC.y, nCz = -2.0f * cC.z;
        float nDx = -2.0f * cD.x, nDy = -2.0f * cD.y, nDz = -2.0f * cD.z;
        int jb = bcls[0] << 12;
        const float4* pb4 = (const float4*)(pos + (size_t)jb * 3);

#define TEST1(NX, NY, NZ, SW, CI, SP, PX, PY, PZ, J) { \
    float d2 = __builtin_fmaf((NX), (PX), __builtin_fmaf((NY), (PY), \
               __builtin_fmaf((NZ), (PZ), (SW) + (SP)))); \
    if (d2 <= R2) push_hit(CI, d2, J, acnt, lists); }
#define TESTP(PX, PY, PZ, J) { \
    float sp = __builtin_fmaf((PX), (PX), __builtin_fmaf((PY), (PY), (PZ) * (PZ))); \
    TEST1(nAx, nAy, nAz, cA.w, 0, sp, PX, PY, PZ, J) \
    TEST1(nBx, nBy, nBz, cB.w, 1, sp, PX, PY, PZ, J) \
    TEST1(nCx, nCy, nCz, cC.w, 2, sp, PX, PY, PZ, J) \
    TEST1(nDx, nDy, nDz, cD.w, 3, sp, PX, PY, PZ, J) }

        #pragma unroll
        for (int it = 0; it < 4; it++) {
            int tq = it * 256 + tid;                   // quad-point index 0..1023
            float4 q0 = pb4[tq * 3], q1 = pb4[tq * 3 + 1], q2 = pb4[tq * 3 + 2];
            int j0 = jb + tq * 4;
            TESTP(q0.x, q0.y, q0.z, j0)
            TESTP(q0.w, q1.x, q1.y, j0 + 1)
            TESTP(q1.z, q1.w, q2.x, j0 + 2)
            TESTP(q2.y, q2.z, q2.w, j0 + 3)
        }
#undef TESTP
#undef TEST1
    } else {
        // rare mixed-cloud block: per-wave scan of own cloud from global (FMA form)
        float nx = -2.0f * cx, ny = -2.0f * cy, nz = -2.0f * cz;
        for (int t = l; t < PCLOUD; t += 64) {
            int j = base + t;
            float px = pos[j * 3], py = pos[j * 3 + 1], pz = pos[j * 3 + 2];
            float sp = __builtin_fmaf(px, px, __builtin_fmaf(py, py, pz * pz));
            float d2 = __builtin_fmaf(nx, px, __builtin_fmaf(ny, py,
                       __builtin_fmaf(nz, pz, sc + sp)));
            if (d2 <= R2) push_hit(w, d2, j, acnt, lists);
        }
    }
    __syncthreads();   // cross-wave list visibility

    int c = acnt[w];
    int nsel = c < KNBR ? c : KNBR;
    u64* mylist = lists + w * CAP;

    // ---- phase B: select the 32 smallest (d2,idx) keys (set only; order free) ----
    int selj = -1;
    if (c <= KNBR) {
        if (l < c) selj = (int)(u32)mylist[l];
    } else if (c <= CAP) {
        u64 kk[7];
        int bk[7];
        if (l < 32) hist[w * 32 + l] = 0;              // same-wave LDS: ordered
        #pragma unroll
        for (int i = 0; i < 7; i++) kk[i] = (l + i * 64 < c) ? mylist[l + i * 64] : ~0ull;
        #pragma unroll
        for (int i = 0; i < 7; i++) {                  // build d2 histogram (this wave only)
            bk[i] = 32;
            if (kk[i] != ~0ull) {
                bk[i] = key_bucket(kk[i]);
                atomicAdd(&hist[w * 32 + bk[i]], 1u);
            }
        }
        int hv = (l < 32) ? (int)hist[w * 32 + l] : 0; // atomics above are same-wave: ordered
        #pragma unroll
        for (int off = 1; off <= 16; off <<= 1) {   // inclusive scan, lanes 0..31
            int o = __shfl_up(hv, off);
            if (l >= off) hv += o;
        }
        u64 ge = __ballot((l < 32) && (hv >= KNBR));
        int B = __ffsll((unsigned long long)ge) - 1;        // threshold bucket
        int S = (B == 0) ? 0 : __shfl(hv, B - 1);           // count strictly below B
        #pragma unroll
        for (int i = 0; i < 7; i++) {                       // bulk-select below B
            if (kk[i] != ~0ull) {
                if (bk[i] < B) { int p = atomicAdd(&cnt2[w], 1); nbrl[w * 32 + p] = (int)(u32)kk[i]; }
                if (bk[i] != B) kk[i] = ~0ull;              // keep only bucket-B keys
            }
        }
        int need = KNBR - S;                                // equalized buckets: ~1-4 rounds
        u64 last = 0;
        for (int r = 0; r < need; r++) {
            u64 mn = ~0ull;
            #pragma unroll
            for (int i = 0; i < 7; i++) if (kk[i] > last && kk[i] < mn) mn = kk[i];
            mn = wave_min_u64(mn);
            if (l == 0) nbrl[w * 32 + S + r] = (int)(u32)mn;
            last = mn;
        }
        if (l < KNBR) selj = nbrl[w * 32 + l];
    } else {
        // overflow fallback (never taken for uniform data): streaming 32-round argmin
        float nx = -2.0f * cx, ny = -2.0f * cy, nz = -2.0f * cz;
        u64 last = 0;
        for (int r = 0; r < KNBR; r++) {
            u64 mn = ~0ull;
            for (int t = l; t < PCLOUD; t += 64) {
                int j = base + t;
                float px = pos[j * 3], py = pos[j * 3 + 1], pz = pos[j * 3 + 2];
                float sp = __builtin_fmaf(px, px, __builtin_fmaf(py, py, pz * pz));
                float d2 = __builtin_fmaf(nx, px, __builtin_fmaf(ny, py,
                           __builtin_fmaf(nz, pz, sc + sp)));
                if (d2 <= R2) { u64 kf = d2key(d2, j); if (kf > last && kf < mn) mn = kf; }
            }
            mn = wave_min_u64(mn);
            if (l == r) selj = (int)(u32)mn;
            last = mn;
        }
    }
    __syncthreads();   // LAST barrier: lists/hist dead; sA becomes the (wave-private) A-tile

    // ---- gather 32 feat rows per wave (XOR 16B-chunk swizzle); rows are wave-private.
    //      h-branched compile-time unroll: all x loads issue together (no serial chain).
    {
        int h = l & 1, rl = l >> 1;
        int row = w * 32 + rl;
        int j = __shfl(selj, rl);
        int xv = row & 7;
        uint4* dst = sA4 + row * 16;
        uint4 z; z.x = z.y = z.z = z.w = 0;
        if (j >= 0) {
            const float4* sx = (const float4*)(x + (size_t)j * DIN);
            if (h == 0) {
                float4 f[12];
                #pragma unroll
                for (int i = 0; i < 12; i++) f[i] = sx[i];
                #pragma unroll
                for (int c0 = 0; c0 < 6; c0++) {
                    uint4 pv;
                    pv.x = cvtpk(f[c0 * 2].x, f[c0 * 2].y);
                    pv.y = cvtpk(f[c0 * 2].z, f[c0 * 2].w);
                    pv.z = cvtpk(f[c0 * 2 + 1].x, f[c0 * 2 + 1].y);
                    pv.w = cvtpk(f[c0 * 2 + 1].z, f[c0 * 2 + 1].w);
                    dst[c0 ^ xv] = pv;
                }
            } else {
                float4 f[4];
                #pragma unroll
                for (int i = 0; i < 4; i++) f[i] = sx[12 + i];
                float rx = pos[j * 3] - cx, ry = pos[j * 3 + 1] - cy, rz = pos[j * 3 + 2] - cz;
                #pragma unroll
                for (int c0 = 0; c0 < 2; c0++) {
                    uint4 pv;
                    pv.x = cvtpk(f[c0 * 2].x, f[c0 * 2].y);
                    pv.y = cvtpk(f[c0 * 2].z, f[c0 * 2].w);
                    pv.z = cvtpk(f[c0 * 2 + 1].x, f[c0 * 2 + 1].y);
                    pv.w = cvtpk(f[c0 * 2 + 1].z, f[c0 * 2 + 1].w);
                    dst[(6 + c0) ^ xv] = pv;
                }
                uint4 rc; rc.x = cvtpk(rx, ry); rc.y = cvtpk(rz, 0.0f); rc.z = 0; rc.w = 0;
                dst[8 ^ xv] = rc;
                dst[9 ^ xv] = z; dst[10 ^ xv] = z; dst[11 ^ xv] = z;
            }
        } else {
            if (h == 0) {
                #pragma unroll
                for (int c0 = 0; c0 < 6; c0++) dst[c0 ^ xv] = z;
            } else {
                #pragma unroll
                for (int c0 = 6; c0 < 12; c0++) dst[c0 ^ xv] = z;
            }
        }
    }

    int m16 = l & 15, quad = l >> 4;
    int r0 = w * 32;
    const floatx4 vzero = {0.f, 0.f, 0.f, 0.f};

#define LDB(BLK, CB, W, RS, COL, KR) \
    (WS ? ldB_ws(ws4, (BLK), (CB), m16) : ldB_fb((W), (RS), (COL), (CB), (KR)))

// h-epilogue for GEMM1/2: relu(acc+bias) -> bf16 pair writes into swizzled sA rows
#define EPI12(BPTR, S, ACC) { \
    float4 bb = ((const float4*)(BPTR))[(S) * 4 + quad]; \
    _Pragma("unroll") \
    for (int t = 0; t < 2; t++) { \
        int rr = r0 + t * 16 + m16; \
        uint2 pv; \
        pv.x = cvtpk(fmaxf(ACC[t][0] + bb.x, 0.f), fmaxf(ACC[t][1] + bb.y, 0.f)); \
        pv.y = cvtpk(fmaxf(ACC[t][2] + bb.z, 0.f), fmaxf(ACC[t][3] + bb.w, 0.f)); \
        *(uint2*)(smem + rr * 256 + ((((S) * 2 + (quad >> 1)) ^ (rr & 7)) << 4) + ((quad & 1) << 3)) = pv; \
    } }

    // ==== GEMM1: h1 = relu(feat @ W1 + b1), K=96, swapped operands, 8 steps, 2-deep ====
    {
        bf16x8 a1[3][2];
        #pragma unroll
        for (int ki = 0; ki < 3; ki++)
            #pragma unroll
            for (int t = 0; t < 2; t++) {
                int row = r0 + t * 16 + m16;
                a1[ki][t] = __builtin_bit_cast(bf16x8, sA4[row * 16 + ((ki * 4 + quad) ^ (row & 7))]);
            }
        uint4 p0[3], p1[3];
        #pragma unroll
        for (int ki = 0; ki < 3; ki++) p0[ki] = LDB(0, ki * 4 + quad, W1, 128, m16, 67);
        #pragma unroll
        for (int ki = 0; ki < 3; ki++) p1[ki] = LDB(1, ki * 4 + quad, W1, 128, 16 + m16, 67);
        #pragma unroll
        for (int s = 0; s < 8; s += 2) {
            {
                floatx4 acc[2] = {vzero, vzero};
                __builtin_amdgcn_s_setprio(1);
                #pragma unroll
                for (int ki = 0; ki < 3; ki++) {
                    bf16x8 b = __builtin_bit_cast(bf16x8, p0[ki]);
                    #pragma unroll
                    for (int t = 0; t < 2; t++)
                        acc[t] = __builtin_amdgcn_mfma_f32_16x16x32_bf16(b, a1[ki][t], acc[t], 0, 0, 0);
                }
                __builtin_amdgcn_s_setprio(0);
                if (s + 2 < 8) {
                    #pragma unroll
                    for (int ki = 0; ki < 3; ki++)
                        p0[ki] = LDB(s + 2, ki * 4 + quad, W1, 128, (s + 2) * 16 + m16, 67);
                }
                EPI12(b1, s, acc);
            }
            {
                floatx4 acc[2] = {vzero, vzero};
                __builtin_amdgcn_s_setprio(1);
                #pragma unroll
                for (int ki = 0; ki < 3; ki++) {
                    bf16x8 b = __builtin_bit_cast(bf16x8, p1[ki]);
                    #pragma unroll
                    for (int t = 0; t < 2; t++)
                        acc[t] = __builtin_amdgcn_mfma_f32_16x16x32_bf16(b, a1[ki][t], acc[t], 0, 0, 0);
                }
                __builtin_amdgcn_s_setprio(0);
                if (s + 3 < 8) {
                    #pragma unroll
                    for (int ki = 0; ki < 3; ki++)
                        p1[ki] = LDB(s + 3, ki * 4 + quad, W1, 128, (s + 3) * 16 + m16, 67);
                }
                EPI12(b1, s + 1, acc);
            }
        }
    }

    // ==== GEMM2: h2 = relu(h1 @ W2 + b2), K=128, swapped operands, 8 steps, 2-deep ====
    {
        bf16x8 a2[4][2];
        #pragma unroll
        for (int ki = 0; ki < 4; ki++)
            #pragma unroll
            for (int t = 0; t < 2; t++) {
                int row = r0 + t * 16 + m16;
                a2[ki][t] = __builtin_bit_cast(bf16x8, sA4[row * 16 + ((ki * 4 + quad) ^ (row & 7))]);
            }
        uint4 p0[4], p1[4];
        #pragma unroll
        for (int ki = 0; ki < 4; ki++) p0[ki] = LDB(8, ki * 4 + quad, W2, 128, m16, 128);
        #pragma unroll
        for (int ki = 0; ki < 4; ki++) p1[ki] = LDB(9, ki * 4 + quad, W2, 128, 16 + m16, 128);
        #pragma unroll
        for (int s = 0; s < 8; s += 2) {
            {
                floatx4 acc[2] = {vzero, vzero};
                __builtin_amdgcn_s_setprio(1);
                #pragma unroll
                for (int ki = 0; ki < 4; ki++) {
                    bf16x8 b = __builtin_bit_cast(bf16x8, p0[ki]);
                    #pragma unroll
                    for (int t = 0; t < 2; t++)
                        acc[t] = __builtin_amdgcn_mfma_f32_16x16x32_bf16(b, a2[ki][t], acc[t], 0, 0, 0);
                }
                __builtin_amdgcn_s_setprio(0);
                if (s + 2 < 8) {
                    #pragma unroll
                    for (int ki = 0; ki < 4; ki++)
                        p0[ki] = LDB(8 + s + 2, ki * 4 + quad, W2, 128, (s + 2) * 16 + m16, 128);
                }
                EPI12(b2, s, acc);
            }
            {
                floatx4 acc[2] = {vzero, vzero};
                __builtin_amdgcn_s_setprio(1);
                #pragma unroll
                for (int ki = 0; ki < 4; ki++) {
                    bf16x8 b = __builtin_bit_cast(bf16x8, p1[ki]);
                    #pragma unroll
                    for (int t = 0; t < 2; t++)
                        acc[t] = __builtin_amdgcn_mfma_f32_16x16x32_bf16(b, a2[ki][t], acc[t], 0, 0, 0);
                }
                __builtin_amdgcn_s_setprio(0);
                if (s + 3 < 8) {
                    #pragma unroll
                    for (int ki = 0; ki < 4; ki++)
                        p1[ki] = LDB(8 + s + 3, ki * 4 + quad, W2, 128, (s + 3) * 16 + m16, 128);
                }
                EPI12(b2, s + 1, acc);
            }
        }
    }

// GEMM3 epilogue: masked max over this wave's 32 rows, reduce across quads, store
#define EPI3(S, ACC) { \
    int col = (S) * 16 + m16; \
    float bias = b3[col]; \
    float mv = 0.0f; \
    _Pragma("unroll") \
    for (int t = 0; t < 2; t++) \
        _Pragma("unroll") \
        for (int i = 0; i < 4; i++) { \
            int k = t * 16 + quad * 4 + i; \
            float v = fmaxf(ACC[t][i] + bias, 0.0f); \
            if (k < nsel) mv = fmaxf(mv, v); \
        } \
    mv = fmaxf(mv, __shfl_xor(mv, 16)); \
    mv = fmaxf(mv, __shfl_xor(mv, 32)); \
    if (quad == 0) out[(m0 + w) * 256 + col] = mv; }

    // ==== GEMM3: out = maxpool(relu(h2 @ W3 + b3)), K=128, N=256, 16 steps, 2-deep ====
    {
        bf16x8 a3[4][2];
        #pragma unroll
        for (int ki = 0; ki < 4; ki++)
            #pragma unroll
            for (int t = 0; t < 2; t++) {
                int row = r0 + t * 16 + m16;
                a3[ki][t] = __builtin_bit_cast(bf16x8, sA4[row * 16 + ((ki * 4 + quad) ^ (row & 7))]);
            }
        uint4 p0[4], p1[4];
        #pragma unroll
        for (int ki = 0; ki < 4; ki++) p0[ki] = LDB(16, ki * 4 + quad, W3, 256, m16, 128);
        #pragma unroll
        for (int ki = 0; ki < 4; ki++) p1[ki] = LDB(17, ki * 4 + quad, W3, 256, 16 + m16, 128);
        #pragma unroll
        for (int s = 0; s < 16; s += 2) {
            {
                floatx4 acc[2] = {vzero, vzero};
                __builtin_amdgcn_s_setprio(1);
                #pragma unroll
                for (int ki = 0; ki < 4; ki++) {
                    bf16x8 b = __builtin_bit_cast(bf16x8, p0[ki]);
                    #pragma unroll
                    for (int t = 0; t < 2; t++)
                        acc[t] = __builtin_amdgcn_mfma_f32_16x16x32_bf16(a3[ki][t], b, acc[t], 0, 0, 0);
                }
                __builtin_amdgcn_s_setprio(0);
                if (s + 2 < 16) {
                    #pragma unroll
                    for (int ki = 0; ki < 4; ki++)
                        p0[ki] = LDB(16 + s + 2, ki * 4 + quad, W3, 256, (s + 2) * 16 + m16, 128);
                }
                EPI3(s, acc);
            }
            {
                floatx4 acc[2] = {vzero, vzero};
                __builtin_amdgcn_s_setprio(1);
                #pragma unroll
                for (int ki = 0; ki < 4; ki++) {
                    bf16x8 b = __builtin_bit_cast(bf16x8, p1[ki]);
                    #pragma unroll
                    for (int t = 0; t < 2; t++)
                        acc[t] = __builtin_amdgcn_mfma_f32_16x16x32_bf16(a3[ki][t], b, acc[t], 0, 0, 0);
                }
                __builtin_amdgcn_s_setprio(0);
                if (s + 3 < 16) {
                    #pragma unroll
                    for (int ki = 0; ki < 4; ki++)
                        p1[ki] = LDB(16 + s + 3, ki * 4 + quad, W3, 256, (s + 3) * 16 + m16, 128);
                }
                EPI3(s + 1, acc);
            }
        }
    }
#undef LDB
#undef EPI12
#undef EPI3
}

extern "C" void kernel_launch(void* const* d_in, const int* in_sizes, int n_in,
                              void* d_out, int out_size, void* d_ws, size_t ws_size,
                              hipStream_t stream) {
    const float* x     = (const float*)d_in[0];
    const float* pos   = (const float*)d_in[1];
    const int*   batch = (const int*)d_in[2];
    const int*   idx   = (const int*)d_in[3];
    const float* W1    = (const float*)d_in[4];
    const float* b1    = (const float*)d_in[5];
    const float* W2    = (const float*)d_in[6];
    const float* b2    = (const float*)d_in[7];
    const float* W3    = (const float*)d_in[8];
    const float* b3    = (const float*)d_in[9];
    float* out = (float*)d_out;
    uint4* ws4 = (uint4*)d_ws;

    if (ws_size >= 131072) {
        hipLaunchKernelGGL(prep_kernel, dim3(32), dim3(256), 0, stream, W1, W2, W3, ws4);
        hipLaunchKernelGGL((sa_kernel<true>), dim3(MCENT / 4), dim3(256), 0, stream,
                           x, pos, batch, idx, W1, b1, W2, b2, W3, b3, ws4, out);
    } else {
        hipLaunchKernelGGL((sa_kernel<false>), dim3(MCENT / 4), dim3(256), 0, stream,
                           x, pos, batch, idx, W1, b1, W2, b2, W3, b3, ws4, out);
    }
}